// Round 3
// baseline (1088.129 us; speedup 1.0000x reference)
//
#include <hip/hip_runtime.h>
#include <hip/hip_bf16.h>

// DynamicRouterMoE: N=8192 tokens, C=1024, Hdim=4096, E=16, top-2.
// R2: + bijective XCD-aware block swizzle (T1) on both GEMMs,
//     + split-K x2 on gemm2 (supply 1024 -> 2048 active blocks; epilogue is
//       already atomicAdd so split-K is structurally free).

typedef __attribute__((ext_vector_type(4))) float f32x4;
typedef __attribute__((ext_vector_type(8))) __bf16 bf16x8;
typedef __attribute__((ext_vector_type(8))) unsigned short u16x8;

#define NEXP 16
#define CAP  2048
#define CDIM 1024
#define HDIM 4096
#define BM 128
#define BN 128
#define BK 64
#define KS2 2    // split-K factor for gemm2

__device__ __forceinline__ unsigned short f2bf(float f) {
  return __builtin_bit_cast(unsigned short, (__bf16)f);
}

// LDS tile [row][BK] bf16 (128B rows), 16B quads XOR-swizzled by row pair.
__device__ __forceinline__ int swz(int row, int b) {
  return row * (BK * 2) + (b ^ (((row >> 1) & 7) << 4));
}

typedef __attribute__((address_space(3))) void  lds_void;
typedef __attribute__((address_space(1))) const void gbl_void;
__device__ __forceinline__ void gload16(const void* g, void* l) {
  __builtin_amdgcn_global_load_lds((gbl_void*)g, (lds_void*)l, 16, 0, 0);
}

// Bijective XCD swizzle (m204 simple form; requires nwg % 8 == 0, true for
// both GEMM grids): XCD k processes a contiguous chunk of work ids.
__device__ __forceinline__ void xcd_remap(int& bx, int& by, int& bz) {
  const int gx = gridDim.x, gy = gridDim.y;
  const int nwg = gx * gy * gridDim.z;
  int flat = blockIdx.x + gx * (blockIdx.y + gy * blockIdx.z);
  flat = (flat & 7) * (nwg >> 3) + (flat >> 3);
  bx = flat % gx;
  const int t = flat / gx;
  by = t % gy;
  bz = t / gy;
}

// ---------------- router: logits(fp64) -> top2 -> softmax -> lists ----------
__global__ __launch_bounds__(64) void router_kernel(
    const float* __restrict__ x, const float* __restrict__ wr,
    float* __restrict__ pair_w, int* __restrict__ counts,
    int* __restrict__ lists)
{
  const int n = blockIdx.x;
  const int l = threadIdx.x;
  const float* xrow = x + (size_t)n * CDIM;
  double acc[NEXP];
#pragma unroll
  for (int e = 0; e < NEXP; e++) acc[e] = 0.0;
  for (int it = 0; it < CDIM / 64; it++) {
    const int c = l + it * 64;
    const double xv = (double)xrow[c];
    const float* w = wr + c * NEXP;
#pragma unroll
    for (int e = 0; e < NEXP; e++) acc[e] += xv * (double)w[e];
  }
#pragma unroll
  for (int e = 0; e < NEXP; e++) {
    double v = acc[e];
    for (int off = 32; off > 0; off >>= 1) v += __shfl_xor(v, off, 64);
    acc[e] = v;
  }
  if (l == 0) {
    int e0 = 0; double b0 = acc[0];
    for (int e = 1; e < NEXP; e++) if (acc[e] > b0) { b0 = acc[e]; e0 = e; }
    int e1 = -1; double b1v = -1e300;
    for (int e = 0; e < NEXP; e++) {
      if (e == e0) continue;
      if (acc[e] > b1v) { b1v = acc[e]; e1 = e; }
    }
    const double d = exp(b1v - b0);
    pair_w[2 * n]     = (float)(1.0 / (1.0 + d));
    pair_w[2 * n + 1] = (float)(d / (1.0 + d));
    int p0 = atomicAdd(&counts[e0], 1);
    if (p0 < CAP) lists[e0 * CAP + p0] = 2 * n;
    int p1 = atomicAdd(&counts[e1], 1);
    if (p1 < CAP) lists[e1 * CAP + p1] = 2 * n + 1;
  }
}

// ---------------- convert x -> bf16 ----------------------------------------
__global__ __launch_bounds__(256) void cvt_x_kernel(
    const float* __restrict__ x, unsigned short* __restrict__ xb, int n8)
{
  const int i = blockIdx.x * 256 + threadIdx.x;
  if (i >= n8) return;
  float4 a = ((const float4*)x)[2 * i];
  float4 b = ((const float4*)x)[2 * i + 1];
  u16x8 v;
  v[0] = f2bf(a.x); v[1] = f2bf(a.y); v[2] = f2bf(a.z); v[3] = f2bf(a.w);
  v[4] = f2bf(b.x); v[5] = f2bf(b.y); v[6] = f2bf(b.z); v[7] = f2bf(b.w);
  ((u16x8*)xb)[i] = v;
}

// ------------- transpose+convert: src fp32 [K][Nn] -> dst bf16 [Nn][K] ------
__global__ __launch_bounds__(256) void transpose_cvt_kernel(
    const float* __restrict__ src, unsigned short* __restrict__ dst,
    int K, int Nn)
{
  __shared__ __align__(16) unsigned short tile[64][72];  // +8 pad
  const size_t eoff = (size_t)blockIdx.z * K * Nn;
  const float* S = src + eoff;
  unsigned short* D = dst + eoff;
  const int n0 = blockIdx.x * 64, k0 = blockIdx.y * 64;
  const int t = threadIdx.x;
  {
    const int nl = (t & 15) * 4, kr = t >> 4;
#pragma unroll
    for (int p = 0; p < 4; p++) {
      const int k = kr + p * 16;
      float4 v = *(const float4*)(S + (size_t)(k0 + k) * Nn + n0 + nl);
      tile[nl + 0][k] = f2bf(v.x);
      tile[nl + 1][k] = f2bf(v.y);
      tile[nl + 2][k] = f2bf(v.z);
      tile[nl + 3][k] = f2bf(v.w);
    }
  }
  __syncthreads();
  {
    const int kq = (t & 7) * 8, nr = t >> 3;
#pragma unroll
    for (int p = 0; p < 2; p++) {
      const int n = nr + p * 32;
      u16x8 v = *(const u16x8*)&tile[n][kq];
      *(u16x8*)(D + (size_t)(n0 + n) * K + k0 + kq) = v;
    }
  }
}

// ---------------- GEMM1 (bf16, global_load_lds staging) ---------------------
// H[pair] = relu(xb[token] @ w1b[e]^T + b1[e]);  w1b is [H][C] k-contiguous.
__global__ __launch_bounds__(256) void gemm1_async_kernel(
    const unsigned short* __restrict__ xb, const unsigned short* __restrict__ wb,
    const float* __restrict__ b1, const int* __restrict__ counts,
    const int* __restrict__ lists, unsigned short* __restrict__ Hb)
{
  int bx, by, bz;
  xcd_remap(bx, by, bz);
  const int e = bz;
  int cnt = counts[e]; if (cnt > CAP) cnt = CAP;
  const int m0 = by * BM;
  if (m0 >= cnt) return;
  const int n0 = bx * BN;
  const int* list = lists + e * CAP;
  const unsigned short* W = wb + (size_t)e * CDIM * HDIM;

  __shared__ __align__(16) unsigned short As[BM * BK];
  __shared__ __align__(16) unsigned short Bs[BN * BK];

  const int t = threadIdx.x, wid = t >> 6, lane = t & 63;
  const char* ag[4]; const char* bg[4];
  unsigned short* al[4]; unsigned short* bl[4];
#pragma unroll
  for (int i = 0; i < 4; i++) {
    const int r = wid * 32 + i * 8 + (lane >> 3);
    const int cb = ((lane & 7) ^ ((r >> 1) & 7)) << 4;
    int ai = m0 + r; if (ai > cnt - 1) ai = cnt - 1;
    const int tok = list[ai] >> 1;
    ag[i] = (const char*)(xb + (size_t)tok * CDIM) + cb;
    bg[i] = (const char*)(W + (size_t)(n0 + r) * CDIM) + cb;
    al[i] = As + (wid * 32 + i * 8) * BK;
    bl[i] = Bs + (wid * 32 + i * 8) * BK;
  }

  const int wm = (wid >> 1) * 64, wn = (wid & 1) * 64;
  const int lrow = lane & 15, lgrp = lane >> 4;
  f32x4 acc[4][4] = {};

  for (int kt = 0; kt < CDIM; kt += BK) {
#pragma unroll
    for (int i = 0; i < 4; i++) {
      gload16(ag[i] + kt * 2, al[i]);
      gload16(bg[i] + kt * 2, bl[i]);
    }
    __syncthreads();
#pragma unroll
    for (int kk = 0; kk < 2; kk++) {
      bf16x8 af[4], bfr[4];
      const int kb = (kk * 32 + lgrp * 8) * 2;
#pragma unroll
      for (int i = 0; i < 4; i++)
        af[i] = *(const bf16x8*)((const char*)As + swz(wm + i * 16 + lrow, kb));
#pragma unroll
      for (int j = 0; j < 4; j++)
        bfr[j] = *(const bf16x8*)((const char*)Bs + swz(wn + j * 16 + lrow, kb));
#pragma unroll
      for (int i = 0; i < 4; i++)
#pragma unroll
        for (int j = 0; j < 4; j++)
          acc[i][j] = __builtin_amdgcn_mfma_f32_16x16x32_bf16(af[i], bfr[j], acc[i][j], 0, 0, 0);
    }
    __syncthreads();
  }

  int hrow[4][4]; bool valid[4][4];
#pragma unroll
  for (int i = 0; i < 4; i++)
#pragma unroll
    for (int r = 0; r < 4; r++) {
      const int mi = m0 + wm + i * 16 + lgrp * 4 + r;
      valid[i][r] = (mi < cnt);
      hrow[i][r] = list[valid[i][r] ? mi : (cnt - 1)];
    }
#pragma unroll
  for (int j = 0; j < 4; j++) {
    const int col = n0 + wn + j * 16 + lrow;
    const float bias = b1[e * HDIM + col];
#pragma unroll
    for (int i = 0; i < 4; i++)
#pragma unroll
      for (int r = 0; r < 4; r++)
        if (valid[i][r]) {
          float h = acc[i][j][r] + bias;
          h = h > 0.f ? h : 0.f;
          Hb[(size_t)hrow[i][r] * HDIM + col] = f2bf(h);
        }
  }
}

// ---------------- GEMM2 (bf16, split-K, global_load_lds staging) ------------
// out[token] += w_pair * (Hb[pair] @ w2b[e]^T + b2[e]); w2b is [C][H].
__global__ __launch_bounds__(256) void gemm2_async_kernel(
    const unsigned short* __restrict__ Hb, const unsigned short* __restrict__ wb,
    const float* __restrict__ b2, const float* __restrict__ pair_w,
    const int* __restrict__ counts, const int* __restrict__ lists,
    float* __restrict__ out)
{
  int bx, by, bz;
  xcd_remap(bx, by, bz);
  const int e = bz / KS2, ks = bz % KS2;
  int cnt = counts[e]; if (cnt > CAP) cnt = CAP;
  const int m0 = by * BM;
  if (m0 >= cnt) return;
  const int n0 = bx * BN;
  const int* list = lists + e * CAP;
  const unsigned short* W = wb + (size_t)e * HDIM * CDIM;
  const int kbeg = ks * (HDIM / KS2), kend = kbeg + HDIM / KS2;

  __shared__ __align__(16) unsigned short As[BM * BK];
  __shared__ __align__(16) unsigned short Bs[BN * BK];

  const int t = threadIdx.x, wid = t >> 6, lane = t & 63;
  const char* ag[4]; const char* bg[4];
  unsigned short* al[4]; unsigned short* bl[4];
#pragma unroll
  for (int i = 0; i < 4; i++) {
    const int r = wid * 32 + i * 8 + (lane >> 3);
    const int cb = ((lane & 7) ^ ((r >> 1) & 7)) << 4;
    int ai = m0 + r; if (ai > cnt - 1) ai = cnt - 1;
    const int pr = list[ai];
    ag[i] = (const char*)(Hb + (size_t)pr * HDIM) + cb;
    bg[i] = (const char*)(W + (size_t)(n0 + r) * HDIM) + cb;
    al[i] = As + (wid * 32 + i * 8) * BK;
    bl[i] = Bs + (wid * 32 + i * 8) * BK;
  }

  const int wm = (wid >> 1) * 64, wn = (wid & 1) * 64;
  const int lrow = lane & 15, lgrp = lane >> 4;
  f32x4 acc[4][4] = {};

  for (int kt = kbeg; kt < kend; kt += BK) {
#pragma unroll
    for (int i = 0; i < 4; i++) {
      gload16(ag[i] + kt * 2, al[i]);
      gload16(bg[i] + kt * 2, bl[i]);
    }
    __syncthreads();
#pragma unroll
    for (int kk = 0; kk < 2; kk++) {
      bf16x8 af[4], bfr[4];
      const int kb = (kk * 32 + lgrp * 8) * 2;
#pragma unroll
      for (int i = 0; i < 4; i++)
        af[i] = *(const bf16x8*)((const char*)As + swz(wm + i * 16 + lrow, kb));
#pragma unroll
      for (int j = 0; j < 4; j++)
        bfr[j] = *(const bf16x8*)((const char*)Bs + swz(wn + j * 16 + lrow, kb));
#pragma unroll
      for (int i = 0; i < 4; i++)
#pragma unroll
        for (int j = 0; j < 4; j++)
          acc[i][j] = __builtin_amdgcn_mfma_f32_16x16x32_bf16(af[i], bfr[j], acc[i][j], 0, 0, 0);
    }
    __syncthreads();
  }

  // epilogue: +b2 (only from the ks==0 chunk), scale, accumulate into out.
  float wgt[4][4]; int tok[4][4]; bool valid[4][4];
#pragma unroll
  for (int i = 0; i < 4; i++)
#pragma unroll
    for (int r = 0; r < 4; r++) {
      const int mi = m0 + wm + i * 16 + lgrp * 4 + r;
      valid[i][r] = (mi < cnt);
      const int p = list[valid[i][r] ? mi : (cnt - 1)];
      wgt[i][r] = pair_w[p];
      tok[i][r] = p >> 1;
    }
#pragma unroll
  for (int j = 0; j < 4; j++) {
    const int col = n0 + wn + j * 16 + lrow;
    const float bias = (ks == 0) ? b2[e * CDIM + col] : 0.f;
#pragma unroll
    for (int i = 0; i < 4; i++)
#pragma unroll
      for (int r = 0; r < 4; r++)
        if (valid[i][r])
          atomicAdd(out + (size_t)tok[i][r] * CDIM + col,
                    wgt[i][r] * (acc[i][j][r] + bias));
  }
}

// ================= round-0 fallback kernels (fp32 inputs, reg-staged) =======
__global__ __launch_bounds__(256) void gemm1_f32_kernel(
    const float* __restrict__ x, const float* __restrict__ w1,
    const float* __restrict__ b1, const int* __restrict__ counts,
    const int* __restrict__ lists, unsigned short* __restrict__ Hb,
    int e_base, int h_by_pair)
{
  const int e = e_base + blockIdx.z;
  int cnt = counts[e]; if (cnt > CAP) cnt = CAP;
  const int m0 = blockIdx.y * BM;
  if (m0 >= cnt) return;
  const int n0 = blockIdx.x * BN;
  const int* list = lists + e * CAP;
  const float* W = w1 + (size_t)e * CDIM * HDIM;
  __shared__ __align__(16) unsigned short As[BM * BK];
  __shared__ __align__(16) unsigned short Bs[BN * BK];
  const int t = threadIdx.x;
  const int a_row = t >> 1, a_half = t & 1;
  int a_idx = m0 + a_row; if (a_idx > cnt - 1) a_idx = cnt - 1;
  const float* a_src = x + (size_t)(list[a_idx] >> 1) * CDIM + a_half * 32;
  const int b_np = t & 63, b_kg = t >> 6;
  const int wid = t >> 6, lane = t & 63;
  const int wm = (wid >> 1) * 64, wn = (wid & 1) * 64;
  const int lrow = lane & 15, lgrp = lane >> 4;
  f32x4 acc[4][4] = {};
  for (int kt = 0; kt < CDIM; kt += BK) {
    {
      const float* s = a_src + kt;
      u16x8 cv[4];
#pragma unroll
      for (int q = 0; q < 4; q++) {
        float4 v0 = *(const float4*)(s + q * 8);
        float4 v1 = *(const float4*)(s + q * 8 + 4);
        cv[q][0] = f2bf(v0.x); cv[q][1] = f2bf(v0.y);
        cv[q][2] = f2bf(v0.z); cv[q][3] = f2bf(v0.w);
        cv[q][4] = f2bf(v1.x); cv[q][5] = f2bf(v1.y);
        cv[q][6] = f2bf(v1.z); cv[q][7] = f2bf(v1.w);
      }
#pragma unroll
      for (int q = 0; q < 4; q++)
        *(u16x8*)((char*)As + swz(a_row, (a_half * 32 + q * 8) * 2)) = cv[q];
    }
    {
#pragma unroll
      for (int it = 0; it < 2; it++) {
        const int k0 = (b_kg + 4 * it) * 8;
        u16x8 c0, c1;
#pragma unroll
        for (int j = 0; j < 8; j++) {
          float2 v = *(const float2*)(W + (size_t)(kt + k0 + j) * HDIM + n0 + 2 * b_np);
          c0[j] = f2bf(v.x); c1[j] = f2bf(v.y);
        }
        *(u16x8*)((char*)Bs + swz(2 * b_np,     k0 * 2)) = c0;
        *(u16x8*)((char*)Bs + swz(2 * b_np + 1, k0 * 2)) = c1;
      }
    }
    __syncthreads();
#pragma unroll
    for (int kk = 0; kk < 2; kk++) {
      bf16x8 af[4], bfr[4];
      const int kb = (kk * 32 + lgrp * 8) * 2;
#pragma unroll
      for (int i = 0; i < 4; i++)
        af[i] = *(const bf16x8*)((const char*)As + swz(wm + i * 16 + lrow, kb));
#pragma unroll
      for (int j = 0; j < 4; j++)
        bfr[j] = *(const bf16x8*)((const char*)Bs + swz(wn + j * 16 + lrow, kb));
#pragma unroll
      for (int i = 0; i < 4; i++)
#pragma unroll
        for (int j = 0; j < 4; j++)
          acc[i][j] = __builtin_amdgcn_mfma_f32_16x16x32_bf16(af[i], bfr[j], acc[i][j], 0, 0, 0);
    }
    __syncthreads();
  }
  int hrow[4][4]; bool valid[4][4];
#pragma unroll
  for (int i = 0; i < 4; i++)
#pragma unroll
    for (int r = 0; r < 4; r++) {
      const int mi = m0 + wm + i * 16 + lgrp * 4 + r;
      valid[i][r] = (mi < cnt);
      const int idx = valid[i][r] ? mi : (cnt - 1);
      hrow[i][r] = h_by_pair ? list[idx] : idx;
    }
#pragma unroll
  for (int j = 0; j < 4; j++) {
    const int col = n0 + wn + j * 16 + lrow;
    const float bias = b1[e * HDIM + col];
#pragma unroll
    for (int i = 0; i < 4; i++)
#pragma unroll
      for (int r = 0; r < 4; r++)
        if (valid[i][r]) {
          float h = acc[i][j][r] + bias;
          h = h > 0.f ? h : 0.f;
          Hb[(size_t)hrow[i][r] * HDIM + col] = f2bf(h);
        }
  }
}

__global__ __launch_bounds__(256) void gemm2_f32_kernel(
    const unsigned short* __restrict__ Hb, const float* __restrict__ w2,
    const float* __restrict__ b2, const float* __restrict__ pair_w,
    const int* __restrict__ counts, const int* __restrict__ lists,
    float* __restrict__ out, int e_base, int h_by_pair)
{
  const int e = e_base + blockIdx.z;
  int cnt = counts[e]; if (cnt > CAP) cnt = CAP;
  const int m0 = blockIdx.y * BM;
  if (m0 >= cnt) return;
  const int n0 = blockIdx.x * BN;
  const int* list = lists + e * CAP;
  const float* W = w2 + (size_t)e * HDIM * CDIM;
  __shared__ __align__(16) unsigned short As[BM * BK];
  __shared__ __align__(16) unsigned short Bs[BN * BK];
  const int t = threadIdx.x;
  const int a_row = t >> 1, a_half = t & 1;
  int a_idx = m0 + a_row; if (a_idx > cnt - 1) a_idx = cnt - 1;
  const unsigned short* a_src =
      Hb + (size_t)(h_by_pair ? list[a_idx] : a_idx) * HDIM + a_half * 32;
  const int b_np = t & 63, b_kg = t >> 6;
  const int wid = t >> 6, lane = t & 63;
  const int wm = (wid >> 1) * 64, wn = (wid & 1) * 64;
  const int lrow = lane & 15, lgrp = lane >> 4;
  f32x4 acc[4][4] = {};
  for (int kt = 0; kt < HDIM; kt += BK) {
    {
      const unsigned short* s = a_src + kt;
#pragma unroll
      for (int q = 0; q < 4; q++) {
        u16x8 v = *(const u16x8*)(s + q * 8);
        *(u16x8*)((char*)As + swz(a_row, (a_half * 32 + q * 8) * 2)) = v;
      }
    }
    {
#pragma unroll
      for (int it = 0; it < 2; it++) {
        const int k0 = (b_kg + 4 * it) * 8;
        u16x8 c0, c1;
#pragma unroll
        for (int j = 0; j < 8; j++) {
          float2 v = *(const float2*)(W + (size_t)(kt + k0 + j) * CDIM + n0 + 2 * b_np);
          c0[j] = f2bf(v.x); c1[j] = f2bf(v.y);
        }
        *(u16x8*)((char*)Bs + swz(2 * b_np,     k0 * 2)) = c0;
        *(u16x8*)((char*)Bs + swz(2 * b_np + 1, k0 * 2)) = c1;
      }
    }
    __syncthreads();
#pragma unroll
    for (int kk = 0; kk < 2; kk++) {
      bf16x8 af[4], bfr[4];
      const int kb = (kk * 32 + lgrp * 8) * 2;
#pragma unroll
      for (int i = 0; i < 4; i++)
        af[i] = *(const bf16x8*)((const char*)As + swz(wm + i * 16 + lrow, kb));
#pragma unroll
      for (int j = 0; j < 4; j++)
        bfr[j] = *(const bf16x8*)((const char*)Bs + swz(wn + j * 16 + lrow, kb));
#pragma unroll
      for (int i = 0; i < 4; i++)
#pragma unroll
        for (int j = 0; j < 4; j++)
          acc[i][j] = __builtin_amdgcn_mfma_f32_16x16x32_bf16(af[i], bfr[j], acc[i][j], 0, 0, 0);
    }
    __syncthreads();
  }
  float wgt[4][4]; int tok[4][4]; bool valid[4][4];
#pragma unroll
  for (int i = 0; i < 4; i++)
#pragma unroll
    for (int r = 0; r < 4; r++) {
      const int mi = m0 + wm + i * 16 + lgrp * 4 + r;
      valid[i][r] = (mi < cnt);
      const int idx = valid[i][r] ? mi : (cnt - 1);
      const int p = list[idx];
      wgt[i][r] = pair_w[p];
      tok[i][r] = p >> 1;
    }
#pragma unroll
  for (int j = 0; j < 4; j++) {
    const int col = n0 + wn + j * 16 + lrow;
    const float bias = b2[e * CDIM + col];
#pragma unroll
    for (int i = 0; i < 4; i++)
#pragma unroll
      for (int r = 0; r < 4; r++)
        if (valid[i][r])
          atomicAdd(out + (size_t)tok[i][r] * CDIM + col,
                    wgt[i][r] * (acc[i][j][r] + bias));
  }
}

extern "C" void kernel_launch(void* const* d_in, const int* in_sizes, int n_in,
                              void* d_out, int out_size, void* d_ws, size_t ws_size,
                              hipStream_t stream)
{
  const float* x  = (const float*)d_in[0];
  const float* wr = (const float*)d_in[1];
  const float* w1 = (const float*)d_in[2];
  const float* b1 = (const float*)d_in[3];
  const float* w2 = (const float*)d_in[4];
  const float* b2 = (const float*)d_in[5];
  float* out = (float*)d_out;

  const int N = in_sizes[0] / CDIM;  // 8192 tokens

  char* ws = (char*)d_ws;
  int* counts = (int*)ws;
  int* lists  = (int*)(ws + 256);
  float* pw   = (float*)(ws + 256 + NEXP * CAP * 4);
  size_t off = 256 + (size_t)NEXP * CAP * 4 + (size_t)2 * N * 4;
  off = (off + 255) & ~(size_t)255;
  unsigned short* xb = (unsigned short*)(ws + off);
  const size_t xb_sz = (size_t)N * CDIM * 2;
  unsigned short* Hb = (unsigned short*)(ws + off + xb_sz);
  const size_t Hb_sz = (size_t)2 * N * HDIM * 2;
  unsigned short* wb = (unsigned short*)(ws + off + xb_sz + Hb_sz);
  const size_t wb_sz = (size_t)NEXP * CDIM * HDIM * 2;

  const size_t need_new = off + xb_sz + Hb_sz + wb_sz;     // ~285 MB
  const size_t need_old = off + Hb_sz;                     // ~134.5 MB

  hipMemsetAsync(d_ws, 0, 64, stream);
  hipMemsetAsync(d_out, 0, (size_t)out_size * 4, stream);

  router_kernel<<<N, 64, 0, stream>>>(x, wr, pw, counts, lists);

  if (ws_size >= need_new) {
    cvt_x_kernel<<<(N * CDIM / 8 + 255) / 256, 256, 0, stream>>>(
        x, xb, N * CDIM / 8);
    transpose_cvt_kernel<<<dim3(HDIM / 64, CDIM / 64, NEXP), 256, 0, stream>>>(
        w1, wb, CDIM, HDIM);
    gemm1_async_kernel<<<dim3(HDIM / BN, CAP / BM, NEXP), 256, 0, stream>>>(
        xb, wb, b1, counts, lists, Hb);
    transpose_cvt_kernel<<<dim3(CDIM / 64, HDIM / 64, NEXP), 256, 0, stream>>>(
        w2, wb, HDIM, CDIM);
    gemm2_async_kernel<<<dim3(CDIM / BN, CAP / BM, NEXP * KS2), 256, 0, stream>>>(
        Hb, wb, b2, pw, counts, lists, out);
  } else if (ws_size >= need_old) {
    unsigned short* Hb0 = (unsigned short*)(ws + off);
    gemm1_f32_kernel<<<dim3(HDIM / BN, CAP / BM, NEXP), 256, 0, stream>>>(
        x, w1, b1, counts, lists, Hb0, 0, 1);
    gemm2_f32_kernel<<<dim3(CDIM / BN, CAP / BM, NEXP), 256, 0, stream>>>(
        Hb0, w2, b2, pw, counts, lists, out, 0, 1);
  }
}

// Round 4
// 1078.004 us; speedup vs baseline: 1.0094x; 1.0094x over previous
//
#include <hip/hip_runtime.h>
#include <hip/hip_bf16.h>

// DynamicRouterMoE: N=8192 tokens, C=1024, Hdim=4096, E=16, top-2.
// R4: depth-2 software pipeline in both GEMMs — double-buffered LDS,
//     counted s_waitcnt vmcnt(8) (never 0 in the loop), raw s_barrier.
//     Keeps R3's XCD swizzle + split-K + global_load_lds(16) staging.

typedef __attribute__((ext_vector_type(4))) float f32x4;
typedef __attribute__((ext_vector_type(8))) __bf16 bf16x8;
typedef __attribute__((ext_vector_type(8))) unsigned short u16x8;

#define NEXP 16
#define CAP  2048
#define CDIM 1024
#define HDIM 4096
#define BM 128
#define BN 128
#define BK 64
#define KS2 2    // split-K factor for gemm2
#define TILE_E (BM * BK)   // elements per LDS tile buffer

__device__ __forceinline__ unsigned short f2bf(float f) {
  return __builtin_bit_cast(unsigned short, (__bf16)f);
}

// LDS tile [row][BK] bf16 (128B rows), 16B quads XOR-swizzled by row pair.
__device__ __forceinline__ int swz(int row, int b) {
  return row * (BK * 2) + (b ^ (((row >> 1) & 7) << 4));
}

typedef __attribute__((address_space(3))) void  lds_void;
typedef __attribute__((address_space(1))) const void gbl_void;
__device__ __forceinline__ void gload16(const void* g, void* l) {
  __builtin_amdgcn_global_load_lds((gbl_void*)g, (lds_void*)l, 16, 0, 0);
}

// Bijective XCD swizzle (requires nwg % 8 == 0; true for both GEMM grids).
__device__ __forceinline__ void xcd_remap(int& bx, int& by, int& bz) {
  const int gx = gridDim.x, gy = gridDim.y;
  const int nwg = gx * gy * gridDim.z;
  int flat = blockIdx.x + gx * (blockIdx.y + gy * blockIdx.z);
  flat = (flat & 7) * (nwg >> 3) + (flat >> 3);
  bx = flat % gx;
  const int t = flat / gx;
  by = t % gy;
  bz = t / gy;
}

// ---------------- router: logits(fp64) -> top2 -> softmax -> lists ----------
__global__ __launch_bounds__(64) void router_kernel(
    const float* __restrict__ x, const float* __restrict__ wr,
    float* __restrict__ pair_w, int* __restrict__ counts,
    int* __restrict__ lists)
{
  const int n = blockIdx.x;
  const int l = threadIdx.x;
  const float* xrow = x + (size_t)n * CDIM;
  double acc[NEXP];
#pragma unroll
  for (int e = 0; e < NEXP; e++) acc[e] = 0.0;
  for (int it = 0; it < CDIM / 64; it++) {
    const int c = l + it * 64;
    const double xv = (double)xrow[c];
    const float* w = wr + c * NEXP;
#pragma unroll
    for (int e = 0; e < NEXP; e++) acc[e] += xv * (double)w[e];
  }
#pragma unroll
  for (int e = 0; e < NEXP; e++) {
    double v = acc[e];
    for (int off = 32; off > 0; off >>= 1) v += __shfl_xor(v, off, 64);
    acc[e] = v;
  }
  if (l == 0) {
    int e0 = 0; double b0 = acc[0];
    for (int e = 1; e < NEXP; e++) if (acc[e] > b0) { b0 = acc[e]; e0 = e; }
    int e1 = -1; double b1v = -1e300;
    for (int e = 0; e < NEXP; e++) {
      if (e == e0) continue;
      if (acc[e] > b1v) { b1v = acc[e]; e1 = e; }
    }
    const double d = exp(b1v - b0);
    pair_w[2 * n]     = (float)(1.0 / (1.0 + d));
    pair_w[2 * n + 1] = (float)(d / (1.0 + d));
    int p0 = atomicAdd(&counts[e0], 1);
    if (p0 < CAP) lists[e0 * CAP + p0] = 2 * n;
    int p1 = atomicAdd(&counts[e1], 1);
    if (p1 < CAP) lists[e1 * CAP + p1] = 2 * n + 1;
  }
}

// ---------------- convert x -> bf16 ----------------------------------------
__global__ __launch_bounds__(256) void cvt_x_kernel(
    const float* __restrict__ x, unsigned short* __restrict__ xb, int n8)
{
  const int i = blockIdx.x * 256 + threadIdx.x;
  if (i >= n8) return;
  float4 a = ((const float4*)x)[2 * i];
  float4 b = ((const float4*)x)[2 * i + 1];
  u16x8 v;
  v[0] = f2bf(a.x); v[1] = f2bf(a.y); v[2] = f2bf(a.z); v[3] = f2bf(a.w);
  v[4] = f2bf(b.x); v[5] = f2bf(b.y); v[6] = f2bf(b.z); v[7] = f2bf(b.w);
  ((u16x8*)xb)[i] = v;
}

// ------------- transpose+convert: src fp32 [K][Nn] -> dst bf16 [Nn][K] ------
__global__ __launch_bounds__(256) void transpose_cvt_kernel(
    const float* __restrict__ src, unsigned short* __restrict__ dst,
    int K, int Nn)
{
  __shared__ __align__(16) unsigned short tile[64][72];  // +8 pad
  const size_t eoff = (size_t)blockIdx.z * K * Nn;
  const float* S = src + eoff;
  unsigned short* D = dst + eoff;
  const int n0 = blockIdx.x * 64, k0 = blockIdx.y * 64;
  const int t = threadIdx.x;
  {
    const int nl = (t & 15) * 4, kr = t >> 4;
#pragma unroll
    for (int p = 0; p < 4; p++) {
      const int k = kr + p * 16;
      float4 v = *(const float4*)(S + (size_t)(k0 + k) * Nn + n0 + nl);
      tile[nl + 0][k] = f2bf(v.x);
      tile[nl + 1][k] = f2bf(v.y);
      tile[nl + 2][k] = f2bf(v.z);
      tile[nl + 3][k] = f2bf(v.w);
    }
  }
  __syncthreads();
  {
    const int kq = (t & 7) * 8, nr = t >> 3;
#pragma unroll
    for (int p = 0; p < 2; p++) {
      const int n = nr + p * 32;
      u16x8 v = *(const u16x8*)&tile[n][kq];
      *(u16x8*)(D + (size_t)(n0 + n) * K + k0 + kq) = v;
    }
  }
}

// Pipelined MFMA macro pieces shared by both GEMMs ---------------------------
#define MFMA_COMPUTE(Abase, Bbase)                                             \
  _Pragma("unroll")                                                            \
  for (int kk = 0; kk < 2; kk++) {                                             \
    bf16x8 af[4], bfr[4];                                                      \
    const int kb = (kk * 32 + lgrp * 8) * 2;                                   \
    _Pragma("unroll")                                                          \
    for (int i = 0; i < 4; i++)                                                \
      af[i] = *(const bf16x8*)((Abase) + swz(wm + i * 16 + lrow, kb));         \
    _Pragma("unroll")                                                          \
    for (int j = 0; j < 4; j++)                                                \
      bfr[j] = *(const bf16x8*)((Bbase) + swz(wn + j * 16 + lrow, kb));        \
    _Pragma("unroll")                                                          \
    for (int i = 0; i < 4; i++)                                                \
      _Pragma("unroll")                                                        \
      for (int j = 0; j < 4; j++)                                              \
        acc[i][j] = __builtin_amdgcn_mfma_f32_16x16x32_bf16(                   \
            af[i], bfr[j], acc[i][j], 0, 0, 0);                                \
  }

// ---------------- GEMM1 (bf16, depth-2 pipelined) ---------------------------
// H[pair] = relu(xb[token] @ w1b[e]^T + b1[e]);  w1b is [H][C] k-contiguous.
__global__ __launch_bounds__(256) void gemm1_async_kernel(
    const unsigned short* __restrict__ xb, const unsigned short* __restrict__ wb,
    const float* __restrict__ b1, const int* __restrict__ counts,
    const int* __restrict__ lists, unsigned short* __restrict__ Hb)
{
  int bx, by, bz;
  xcd_remap(bx, by, bz);
  const int e = bz;
  int cnt = counts[e]; if (cnt > CAP) cnt = CAP;
  const int m0 = by * BM;
  if (m0 >= cnt) return;
  const int n0 = bx * BN;
  const int* list = lists + e * CAP;
  const unsigned short* W = wb + (size_t)e * CDIM * HDIM;

  __shared__ __align__(16) unsigned short As[2 * TILE_E];
  __shared__ __align__(16) unsigned short Bs[2 * TILE_E];

  const int t = threadIdx.x, wid = t >> 6, lane = t & 63;
  const char* ag[4]; const char* bg[4];
  unsigned short* al[4]; unsigned short* bl[4];
#pragma unroll
  for (int i = 0; i < 4; i++) {
    const int r = wid * 32 + i * 8 + (lane >> 3);
    const int cb = ((lane & 7) ^ ((r >> 1) & 7)) << 4;
    int ai = m0 + r; if (ai > cnt - 1) ai = cnt - 1;
    const int tok = list[ai] >> 1;
    ag[i] = (const char*)(xb + (size_t)tok * CDIM) + cb;
    bg[i] = (const char*)(W + (size_t)(n0 + r) * CDIM) + cb;
    al[i] = As + (wid * 32 + i * 8) * BK;
    bl[i] = Bs + (wid * 32 + i * 8) * BK;
  }

  const int wm = (wid >> 1) * 64, wn = (wid & 1) * 64;
  const int lrow = lane & 15, lgrp = lane >> 4;
  f32x4 acc[4][4] = {};

  // prologue: stage tile 0 into buffer 0
#pragma unroll
  for (int i = 0; i < 4; i++) {
    gload16(ag[i], al[i]);
    gload16(bg[i], bl[i]);
  }
  const int NT = CDIM / BK;
  for (int tt = 0; tt < NT - 1; ++tt) {
    const int p = tt & 1;
    const int koff = (tt + 1) * (BK * 2);  // byte advance in global k
#pragma unroll
    for (int i = 0; i < 4; i++) {
      gload16(ag[i] + koff, al[i] + (p ^ 1) * TILE_E);
      gload16(bg[i] + koff, bl[i] + (p ^ 1) * TILE_E);
    }
    asm volatile("s_waitcnt vmcnt(8)" ::: "memory");  // tile tt landed
    asm volatile("s_barrier" ::: "memory");
    const char* Ab = (const char*)As + p * (TILE_E * 2);
    const char* Bb = (const char*)Bs + p * (TILE_E * 2);
    MFMA_COMPUTE(Ab, Bb)
    asm volatile("s_barrier" ::: "memory");           // all reads of buf p done
  }
  {
    const int p = (NT - 1) & 1;
    asm volatile("s_waitcnt vmcnt(0)" ::: "memory");
    asm volatile("s_barrier" ::: "memory");
    const char* Ab = (const char*)As + p * (TILE_E * 2);
    const char* Bb = (const char*)Bs + p * (TILE_E * 2);
    MFMA_COMPUTE(Ab, Bb)
  }

  int hrow[4][4]; bool valid[4][4];
#pragma unroll
  for (int i = 0; i < 4; i++)
#pragma unroll
    for (int r = 0; r < 4; r++) {
      const int mi = m0 + wm + i * 16 + lgrp * 4 + r;
      valid[i][r] = (mi < cnt);
      hrow[i][r] = list[valid[i][r] ? mi : (cnt - 1)];
    }
#pragma unroll
  for (int j = 0; j < 4; j++) {
    const int col = n0 + wn + j * 16 + lrow;
    const float bias = b1[e * HDIM + col];
#pragma unroll
    for (int i = 0; i < 4; i++)
#pragma unroll
      for (int r = 0; r < 4; r++)
        if (valid[i][r]) {
          float h = acc[i][j][r] + bias;
          h = h > 0.f ? h : 0.f;
          Hb[(size_t)hrow[i][r] * HDIM + col] = f2bf(h);
        }
  }
}

// ---------------- GEMM2 (bf16, split-K, depth-2 pipelined) ------------------
// out[token] += w_pair * (Hb[pair] @ w2b[e]^T + b2[e]); w2b is [C][H].
__global__ __launch_bounds__(256) void gemm2_async_kernel(
    const unsigned short* __restrict__ Hb, const unsigned short* __restrict__ wb,
    const float* __restrict__ b2, const float* __restrict__ pair_w,
    const int* __restrict__ counts, const int* __restrict__ lists,
    float* __restrict__ out)
{
  int bx, by, bz;
  xcd_remap(bx, by, bz);
  const int e = bz / KS2, ks = bz % KS2;
  int cnt = counts[e]; if (cnt > CAP) cnt = CAP;
  const int m0 = by * BM;
  if (m0 >= cnt) return;
  const int n0 = bx * BN;
  const int* list = lists + e * CAP;
  const unsigned short* W = wb + (size_t)e * HDIM * CDIM;
  const int kbeg = ks * (HDIM / KS2);

  __shared__ __align__(16) unsigned short As[2 * TILE_E];
  __shared__ __align__(16) unsigned short Bs[2 * TILE_E];

  const int t = threadIdx.x, wid = t >> 6, lane = t & 63;
  const char* ag[4]; const char* bg[4];
  unsigned short* al[4]; unsigned short* bl[4];
#pragma unroll
  for (int i = 0; i < 4; i++) {
    const int r = wid * 32 + i * 8 + (lane >> 3);
    const int cb = ((lane & 7) ^ ((r >> 1) & 7)) << 4;
    int ai = m0 + r; if (ai > cnt - 1) ai = cnt - 1;
    const int pr = list[ai];
    ag[i] = (const char*)(Hb + (size_t)pr * HDIM + kbeg) + cb;
    bg[i] = (const char*)(W + (size_t)(n0 + r) * HDIM + kbeg) + cb;
    al[i] = As + (wid * 32 + i * 8) * BK;
    bl[i] = Bs + (wid * 32 + i * 8) * BK;
  }

  const int wm = (wid >> 1) * 64, wn = (wid & 1) * 64;
  const int lrow = lane & 15, lgrp = lane >> 4;
  f32x4 acc[4][4] = {};

  // prologue
#pragma unroll
  for (int i = 0; i < 4; i++) {
    gload16(ag[i], al[i]);
    gload16(bg[i], bl[i]);
  }
  const int NT = (HDIM / KS2) / BK;
  for (int tt = 0; tt < NT - 1; ++tt) {
    const int p = tt & 1;
    const int koff = (tt + 1) * (BK * 2);
#pragma unroll
    for (int i = 0; i < 4; i++) {
      gload16(ag[i] + koff, al[i] + (p ^ 1) * TILE_E);
      gload16(bg[i] + koff, bl[i] + (p ^ 1) * TILE_E);
    }
    asm volatile("s_waitcnt vmcnt(8)" ::: "memory");
    asm volatile("s_barrier" ::: "memory");
    const char* Ab = (const char*)As + p * (TILE_E * 2);
    const char* Bb = (const char*)Bs + p * (TILE_E * 2);
    MFMA_COMPUTE(Ab, Bb)
    asm volatile("s_barrier" ::: "memory");
  }
  {
    const int p = (NT - 1) & 1;
    asm volatile("s_waitcnt vmcnt(0)" ::: "memory");
    asm volatile("s_barrier" ::: "memory");
    const char* Ab = (const char*)As + p * (TILE_E * 2);
    const char* Bb = (const char*)Bs + p * (TILE_E * 2);
    MFMA_COMPUTE(Ab, Bb)
  }

  // epilogue: +b2 (only from the ks==0 chunk), scale, accumulate into out.
  float wgt[4][4]; int tok[4][4]; bool valid[4][4];
#pragma unroll
  for (int i = 0; i < 4; i++)
#pragma unroll
    for (int r = 0; r < 4; r++) {
      const int mi = m0 + wm + i * 16 + lgrp * 4 + r;
      valid[i][r] = (mi < cnt);
      const int p = list[valid[i][r] ? mi : (cnt - 1)];
      wgt[i][r] = pair_w[p];
      tok[i][r] = p >> 1;
    }
#pragma unroll
  for (int j = 0; j < 4; j++) {
    const int col = n0 + wn + j * 16 + lrow;
    const float bias = (ks == 0) ? b2[e * CDIM + col] : 0.f;
#pragma unroll
    for (int i = 0; i < 4; i++)
#pragma unroll
      for (int r = 0; r < 4; r++)
        if (valid[i][r])
          atomicAdd(out + (size_t)tok[i][r] * CDIM + col,
                    wgt[i][r] * (acc[i][j][r] + bias));
  }
}

// ================= round-0 fallback kernels (fp32 inputs, reg-staged) =======
__global__ __launch_bounds__(256) void gemm1_f32_kernel(
    const float* __restrict__ x, const float* __restrict__ w1,
    const float* __restrict__ b1, const int* __restrict__ counts,
    const int* __restrict__ lists, unsigned short* __restrict__ Hb,
    int e_base, int h_by_pair)
{
  const int e = e_base + blockIdx.z;
  int cnt = counts[e]; if (cnt > CAP) cnt = CAP;
  const int m0 = blockIdx.y * BM;
  if (m0 >= cnt) return;
  const int n0 = blockIdx.x * BN;
  const int* list = lists + e * CAP;
  const float* W = w1 + (size_t)e * CDIM * HDIM;
  __shared__ __align__(16) unsigned short As[TILE_E];
  __shared__ __align__(16) unsigned short Bs[TILE_E];
  const int t = threadIdx.x;
  const int a_row = t >> 1, a_half = t & 1;
  int a_idx = m0 + a_row; if (a_idx > cnt - 1) a_idx = cnt - 1;
  const float* a_src = x + (size_t)(list[a_idx] >> 1) * CDIM + a_half * 32;
  const int b_np = t & 63, b_kg = t >> 6;
  const int wid = t >> 6, lane = t & 63;
  const int wm = (wid >> 1) * 64, wn = (wid & 1) * 64;
  const int lrow = lane & 15, lgrp = lane >> 4;
  f32x4 acc[4][4] = {};
  for (int kt = 0; kt < CDIM; kt += BK) {
    {
      const float* s = a_src + kt;
      u16x8 cv[4];
#pragma unroll
      for (int q = 0; q < 4; q++) {
        float4 v0 = *(const float4*)(s + q * 8);
        float4 v1 = *(const float4*)(s + q * 8 + 4);
        cv[q][0] = f2bf(v0.x); cv[q][1] = f2bf(v0.y);
        cv[q][2] = f2bf(v0.z); cv[q][3] = f2bf(v0.w);
        cv[q][4] = f2bf(v1.x); cv[q][5] = f2bf(v1.y);
        cv[q][6] = f2bf(v1.z); cv[q][7] = f2bf(v1.w);
      }
#pragma unroll
      for (int q = 0; q < 4; q++)
        *(u16x8*)((char*)As + swz(a_row, (a_half * 32 + q * 8) * 2)) = cv[q];
    }
    {
#pragma unroll
      for (int it = 0; it < 2; it++) {
        const int k0 = (b_kg + 4 * it) * 8;
        u16x8 c0, c1;
#pragma unroll
        for (int j = 0; j < 8; j++) {
          float2 v = *(const float2*)(W + (size_t)(kt + k0 + j) * HDIM + n0 + 2 * b_np);
          c0[j] = f2bf(v.x); c1[j] = f2bf(v.y);
        }
        *(u16x8*)((char*)Bs + swz(2 * b_np,     k0 * 2)) = c0;
        *(u16x8*)((char*)Bs + swz(2 * b_np + 1, k0 * 2)) = c1;
      }
    }
    __syncthreads();
    MFMA_COMPUTE((const char*)As, (const char*)Bs)
    __syncthreads();
  }
  int hrow[4][4]; bool valid[4][4];
#pragma unroll
  for (int i = 0; i < 4; i++)
#pragma unroll
    for (int r = 0; r < 4; r++) {
      const int mi = m0 + wm + i * 16 + lgrp * 4 + r;
      valid[i][r] = (mi < cnt);
      const int idx = valid[i][r] ? mi : (cnt - 1);
      hrow[i][r] = h_by_pair ? list[idx] : idx;
    }
#pragma unroll
  for (int j = 0; j < 4; j++) {
    const int col = n0 + wn + j * 16 + lrow;
    const float bias = b1[e * HDIM + col];
#pragma unroll
    for (int i = 0; i < 4; i++)
#pragma unroll
      for (int r = 0; r < 4; r++)
        if (valid[i][r]) {
          float h = acc[i][j][r] + bias;
          h = h > 0.f ? h : 0.f;
          Hb[(size_t)hrow[i][r] * HDIM + col] = f2bf(h);
        }
  }
}

__global__ __launch_bounds__(256) void gemm2_f32_kernel(
    const unsigned short* __restrict__ Hb, const float* __restrict__ w2,
    const float* __restrict__ b2, const float* __restrict__ pair_w,
    const int* __restrict__ counts, const int* __restrict__ lists,
    float* __restrict__ out, int e_base, int h_by_pair)
{
  const int e = e_base + blockIdx.z;
  int cnt = counts[e]; if (cnt > CAP) cnt = CAP;
  const int m0 = blockIdx.y * BM;
  if (m0 >= cnt) return;
  const int n0 = blockIdx.x * BN;
  const int* list = lists + e * CAP;
  const float* W = w2 + (size_t)e * HDIM * CDIM;
  __shared__ __align__(16) unsigned short As[TILE_E];
  __shared__ __align__(16) unsigned short Bs[TILE_E];
  const int t = threadIdx.x;
  const int a_row = t >> 1, a_half = t & 1;
  int a_idx = m0 + a_row; if (a_idx > cnt - 1) a_idx = cnt - 1;
  const unsigned short* a_src =
      Hb + (size_t)(h_by_pair ? list[a_idx] : a_idx) * HDIM + a_half * 32;
  const int b_np = t & 63, b_kg = t >> 6;
  const int wid = t >> 6, lane = t & 63;
  const int wm = (wid >> 1) * 64, wn = (wid & 1) * 64;
  const int lrow = lane & 15, lgrp = lane >> 4;
  f32x4 acc[4][4] = {};
  for (int kt = 0; kt < HDIM; kt += BK) {
    {
      const unsigned short* s = a_src + kt;
#pragma unroll
      for (int q = 0; q < 4; q++) {
        u16x8 v = *(const u16x8*)(s + q * 8);
        *(u16x8*)((char*)As + swz(a_row, (a_half * 32 + q * 8) * 2)) = v;
      }
    }
    {
#pragma unroll
      for (int it = 0; it < 2; it++) {
        const int k0 = (b_kg + 4 * it) * 8;
        u16x8 c0, c1;
#pragma unroll
        for (int j = 0; j < 8; j++) {
          float2 v = *(const float2*)(W + (size_t)(kt + k0 + j) * CDIM + n0 + 2 * b_np);
          c0[j] = f2bf(v.x); c1[j] = f2bf(v.y);
        }
        *(u16x8*)((char*)Bs + swz(2 * b_np,     k0 * 2)) = c0;
        *(u16x8*)((char*)Bs + swz(2 * b_np + 1, k0 * 2)) = c1;
      }
    }
    __syncthreads();
    MFMA_COMPUTE((const char*)As, (const char*)Bs)
    __syncthreads();
  }
  float wgt[4][4]; int tok[4][4]; bool valid[4][4];
#pragma unroll
  for (int i = 0; i < 4; i++)
#pragma unroll
    for (int r = 0; r < 4; r++) {
      const int mi = m0 + wm + i * 16 + lgrp * 4 + r;
      valid[i][r] = (mi < cnt);
      const int idx = valid[i][r] ? mi : (cnt - 1);
      const int p = list[idx];
      wgt[i][r] = pair_w[p];
      tok[i][r] = p >> 1;
    }
#pragma unroll
  for (int j = 0; j < 4; j++) {
    const int col = n0 + wn + j * 16 + lrow;
    const float bias = b2[e * CDIM + col];
#pragma unroll
    for (int i = 0; i < 4; i++)
#pragma unroll
      for (int r = 0; r < 4; r++)
        if (valid[i][r])
          atomicAdd(out + (size_t)tok[i][r] * CDIM + col,
                    wgt[i][r] * (acc[i][j][r] + bias));
  }
}

extern "C" void kernel_launch(void* const* d_in, const int* in_sizes, int n_in,
                              void* d_out, int out_size, void* d_ws, size_t ws_size,
                              hipStream_t stream)
{
  const float* x  = (const float*)d_in[0];
  const float* wr = (const float*)d_in[1];
  const float* w1 = (const float*)d_in[2];
  const float* b1 = (const float*)d_in[3];
  const float* w2 = (const float*)d_in[4];
  const float* b2 = (const float*)d_in[5];
  float* out = (float*)d_out;

  const int N = in_sizes[0] / CDIM;  // 8192 tokens

  char* ws = (char*)d_ws;
  int* counts = (int*)ws;
  int* lists  = (int*)(ws + 256);
  float* pw   = (float*)(ws + 256 + NEXP * CAP * 4);
  size_t off = 256 + (size_t)NEXP * CAP * 4 + (size_t)2 * N * 4;
  off = (off + 255) & ~(size_t)255;
  unsigned short* xb = (unsigned short*)(ws + off);
  const size_t xb_sz = (size_t)N * CDIM * 2;
  unsigned short* Hb = (unsigned short*)(ws + off + xb_sz);
  const size_t Hb_sz = (size_t)2 * N * HDIM * 2;
  unsigned short* wb = (unsigned short*)(ws + off + xb_sz + Hb_sz);
  const size_t wb_sz = (size_t)NEXP * CDIM * HDIM * 2;

  const size_t need_new = off + xb_sz + Hb_sz + wb_sz;     // ~285 MB
  const size_t need_old = off + Hb_sz;                     // ~134.5 MB

  hipMemsetAsync(d_ws, 0, 64, stream);
  hipMemsetAsync(d_out, 0, (size_t)out_size * 4, stream);

  router_kernel<<<N, 64, 0, stream>>>(x, wr, pw, counts, lists);

  if (ws_size >= need_new) {
    cvt_x_kernel<<<(N * CDIM / 8 + 255) / 256, 256, 0, stream>>>(
        x, xb, N * CDIM / 8);
    transpose_cvt_kernel<<<dim3(HDIM / 64, CDIM / 64, NEXP), 256, 0, stream>>>(
        w1, wb, CDIM, HDIM);
    gemm1_async_kernel<<<dim3(HDIM / BN, CAP / BM, NEXP), 256, 0, stream>>>(
        xb, wb, b1, counts, lists, Hb);
    transpose_cvt_kernel<<<dim3(CDIM / 64, HDIM / 64, NEXP), 256, 0, stream>>>(
        w2, wb, HDIM, CDIM);
    gemm2_async_kernel<<<dim3(CDIM / BN, CAP / BM, NEXP * KS2), 256, 0, stream>>>(
        Hb, wb, b2, pw, counts, lists, out);
  } else if (ws_size >= need_old) {
    unsigned short* Hb0 = (unsigned short*)(ws + off);
    gemm1_f32_kernel<<<dim3(HDIM / BN, CAP / BM, NEXP), 256, 0, stream>>>(
        x, w1, b1, counts, lists, Hb0, 0, 1);
    gemm2_f32_kernel<<<dim3(CDIM / BN, CAP / BM, NEXP), 256, 0, stream>>>(
        Hb0, w2, b2, pw, counts, lists, out, 0, 1);
  }
}

// Round 5
// 937.481 us; speedup vs baseline: 1.1607x; 1.1499x over previous
//
#include <hip/hip_runtime.h>
#include <hip/hip_bf16.h>

// DynamicRouterMoE: N=8192 tokens, C=1024, Hdim=4096, E=16, top-2.
// R5: 256x256 8-wave phase-split GEMMs (T3+T4 structure): 4 LDS slots per
//     operand [par][khalf][256][32], one barrier + counted vmcnt(4) per
//     phase, 2-phase issue->consume lead, setprio around MFMA cluster.

typedef __attribute__((ext_vector_type(4))) float f32x4;
typedef __attribute__((ext_vector_type(8))) __bf16 bf16x8;
typedef __attribute__((ext_vector_type(8))) unsigned short u16x8;

#define NEXP 16
#define CAP  2048
#define CDIM 1024
#define HDIM 4096
#define KS2 2            // split-K factor for gemm2
#define BMG 256          // GEMM tile M
#define BNG 256          // GEMM tile N (gemm1); gemm2 also 256
#define SLOT 8192        // elems per LDS slot: 256 rows x 32 k

__device__ __forceinline__ unsigned short f2bf(float f) {
  return __builtin_bit_cast(unsigned short, (__bf16)f);
}

typedef __attribute__((address_space(3))) void  lds_void;
typedef __attribute__((address_space(1))) const void gbl_void;
__device__ __forceinline__ void gload16(const void* g, void* l) {
  __builtin_amdgcn_global_load_lds((gbl_void*)g, (lds_void*)l, 16, 0, 0);
}

// Bijective XCD swizzle (requires nwg % 8 == 0; true for all GEMM grids).
__device__ __forceinline__ void xcd_remap(int& bx, int& by, int& bz) {
  const int gx = gridDim.x, gy = gridDim.y;
  const int nwg = gx * gy * gridDim.z;
  int flat = blockIdx.x + gx * (blockIdx.y + gy * blockIdx.z);
  flat = (flat & 7) * (nwg >> 3) + (flat >> 3);
  bx = flat % gx;
  const int t = flat / gx;
  by = t % gy;
  bz = t / gy;
}

// ---------------- router: logits(fp64) -> top2 -> softmax -> lists ----------
__global__ __launch_bounds__(64) void router_kernel(
    const float* __restrict__ x, const float* __restrict__ wr,
    float* __restrict__ pair_w, int* __restrict__ counts,
    int* __restrict__ lists)
{
  const int n = blockIdx.x;
  const int l = threadIdx.x;
  const float* xrow = x + (size_t)n * CDIM;
  double acc[NEXP];
#pragma unroll
  for (int e = 0; e < NEXP; e++) acc[e] = 0.0;
  for (int it = 0; it < CDIM / 64; it++) {
    const int c = l + it * 64;
    const double xv = (double)xrow[c];
    const float* w = wr + c * NEXP;
#pragma unroll
    for (int e = 0; e < NEXP; e++) acc[e] += xv * (double)w[e];
  }
#pragma unroll
  for (int e = 0; e < NEXP; e++) {
    double v = acc[e];
    for (int off = 32; off > 0; off >>= 1) v += __shfl_xor(v, off, 64);
    acc[e] = v;
  }
  if (l == 0) {
    int e0 = 0; double b0 = acc[0];
    for (int e = 1; e < NEXP; e++) if (acc[e] > b0) { b0 = acc[e]; e0 = e; }
    int e1 = -1; double b1v = -1e300;
    for (int e = 0; e < NEXP; e++) {
      if (e == e0) continue;
      if (acc[e] > b1v) { b1v = acc[e]; e1 = e; }
    }
    const double d = exp(b1v - b0);
    pair_w[2 * n]     = (float)(1.0 / (1.0 + d));
    pair_w[2 * n + 1] = (float)(d / (1.0 + d));
    int p0 = atomicAdd(&counts[e0], 1);
    if (p0 < CAP) lists[e0 * CAP + p0] = 2 * n;
    int p1 = atomicAdd(&counts[e1], 1);
    if (p1 < CAP) lists[e1 * CAP + p1] = 2 * n + 1;
  }
}

// ---------------- convert x -> bf16 ----------------------------------------
__global__ __launch_bounds__(256) void cvt_x_kernel(
    const float* __restrict__ x, unsigned short* __restrict__ xb, int n8)
{
  const int i = blockIdx.x * 256 + threadIdx.x;
  if (i >= n8) return;
  float4 a = ((const float4*)x)[2 * i];
  float4 b = ((const float4*)x)[2 * i + 1];
  u16x8 v;
  v[0] = f2bf(a.x); v[1] = f2bf(a.y); v[2] = f2bf(a.z); v[3] = f2bf(a.w);
  v[4] = f2bf(b.x); v[5] = f2bf(b.y); v[6] = f2bf(b.z); v[7] = f2bf(b.w);
  ((u16x8*)xb)[i] = v;
}

// ------------- transpose+convert: src fp32 [K][Nn] -> dst bf16 [Nn][K] ------
__global__ __launch_bounds__(256) void transpose_cvt_kernel(
    const float* __restrict__ src, unsigned short* __restrict__ dst,
    int K, int Nn)
{
  __shared__ __align__(16) unsigned short tile[64][72];  // +8 pad
  const size_t eoff = (size_t)blockIdx.z * K * Nn;
  const float* S = src + eoff;
  unsigned short* D = dst + eoff;
  const int n0 = blockIdx.x * 64, k0 = blockIdx.y * 64;
  const int t = threadIdx.x;
  {
    const int nl = (t & 15) * 4, kr = t >> 4;
#pragma unroll
    for (int p = 0; p < 4; p++) {
      const int k = kr + p * 16;
      float4 v = *(const float4*)(S + (size_t)(k0 + k) * Nn + n0 + nl);
      tile[nl + 0][k] = f2bf(v.x);
      tile[nl + 1][k] = f2bf(v.y);
      tile[nl + 2][k] = f2bf(v.z);
      tile[nl + 3][k] = f2bf(v.w);
    }
  }
  __syncthreads();
  {
    const int kq = (t & 7) * 8, nr = t >> 3;
#pragma unroll
    for (int p = 0; p < 2; p++) {
      const int n = nr + p * 32;
      u16x8 v = *(const u16x8*)&tile[n][kq];
      *(u16x8*)(D + (size_t)(n0 + n) * K + k0 + kq) = v;
    }
  }
}

// ========= 8-wave 256x256 phase-split GEMM bodies ==========================
// LDS: A slots [par][kh][256][32] then B slots; slot = 16KB.
// Per phase: vmcnt(4); barrier; stage 4 gloads for (t+1,h); 12 ds_read;
// setprio(1); 32 MFMA; setprio(0).

#define STAGE(parx, hx, koffb)                                                 \
  do {                                                                         \
    unsigned short* Ad = &lds[((parx) * 2 + (hx)) * SLOT + w * 512];           \
    unsigned short* Bd = &lds[4 * SLOT + ((parx) * 2 + (hx)) * SLOT + w * 512];\
    gload16(agA0 + (koffb), Ad);                                               \
    gload16(agA1 + (koffb), Ad + 4096);                                        \
    gload16(bgB0 + (koffb), Bd);                                               \
    gload16(bgB1 + (koffb), Bd + 4096);                                        \
  } while (0)

#define COMPUTE(parx, hx)                                                      \
  do {                                                                         \
    const unsigned short* As_ = &lds[((parx) * 2 + (hx)) * SLOT];              \
    const unsigned short* Bs_ = &lds[4 * SLOT + ((parx) * 2 + (hx)) * SLOT];   \
    bf16x8 af[8], bfv[4];                                                      \
    _Pragma("unroll")                                                          \
    for (int mf = 0; mf < 8; mf++)                                             \
      af[mf] = *(const bf16x8*)(As_ + (wr * 128 + mf * 16 + lrow) * 32 + lgrp * 8); \
    _Pragma("unroll")                                                          \
    for (int nf = 0; nf < 4; nf++)                                             \
      bfv[nf] = *(const bf16x8*)(Bs_ + (wc * 64 + nf * 16 + lrow) * 32 + lgrp * 8); \
    __builtin_amdgcn_s_setprio(1);                                             \
    _Pragma("unroll")                                                          \
    for (int mf = 0; mf < 8; mf++)                                             \
      _Pragma("unroll")                                                        \
      for (int nf = 0; nf < 4; nf++)                                           \
        acc[mf][nf] = __builtin_amdgcn_mfma_f32_16x16x32_bf16(                 \
            af[mf], bfv[nf], acc[mf][nf], 0, 0, 0);                            \
    __builtin_amdgcn_s_setprio(0);                                             \
  } while (0)

#define VMCNT4 asm volatile("s_waitcnt vmcnt(4)" ::: "memory")
#define VMCNT0 asm volatile("s_waitcnt vmcnt(0)" ::: "memory")
#define SBAR   asm volatile("s_barrier" ::: "memory")

// ---------------- GEMM1: H[pair] = relu(xb[token] @ w1b[e]^T + b1[e]) -------
__global__ __launch_bounds__(512, 2) void gemm1_8p_kernel(
    const unsigned short* __restrict__ xb, const unsigned short* __restrict__ wb,
    const float* __restrict__ b1, const int* __restrict__ counts,
    const int* __restrict__ lists, unsigned short* __restrict__ Hb)
{
  int bx, by, bz;
  xcd_remap(bx, by, bz);
  const int e = bz;
  int cnt = counts[e]; if (cnt > CAP) cnt = CAP;
  const int m0 = by * BMG;
  if (m0 >= cnt) return;
  const int n0 = bx * BNG;
  const int* list = lists + e * CAP;
  const unsigned short* W = wb + (size_t)e * CDIM * HDIM;

  __shared__ __align__(16) unsigned short lds[8 * SLOT];  // 128 KB

  const int t = threadIdx.x, w = t >> 6, lane = t & 63;
  const int wr = w >> 2, wc = w & 3;          // 2M x 4N waves, each 128x64
  const int lrow = lane & 15, lgrp = lane >> 4;

  // staging: thread covers rows r(j) = j*128 + w*16 + lane/4, quad lane&3
  const int sr0 = w * 16 + (lane >> 2), sr1 = 128 + w * 16 + (lane >> 2);
  int ai0 = m0 + sr0; if (ai0 > cnt - 1) ai0 = cnt - 1;
  int ai1 = m0 + sr1; if (ai1 > cnt - 1) ai1 = cnt - 1;
  const char* agA0 = (const char*)(xb + (size_t)(list[ai0] >> 1) * CDIM) + (lane & 3) * 16;
  const char* agA1 = (const char*)(xb + (size_t)(list[ai1] >> 1) * CDIM) + (lane & 3) * 16;
  const char* bgB0 = (const char*)(W + (size_t)(n0 + sr0) * CDIM) + (lane & 3) * 16;
  const char* bgB1 = (const char*)(W + (size_t)(n0 + sr1) * CDIM) + (lane & 3) * 16;

  f32x4 acc[8][4] = {};

  const int NT = CDIM / 64;  // 16 K-tiles
  STAGE(0, 0, 0);
  STAGE(0, 1, 64);
  for (int tt = 0; tt < NT - 1; ++tt) {
    const int par = tt & 1;
    const int kofn = (tt + 1) * 128;
#pragma unroll
    for (int h = 0; h < 2; ++h) {
      VMCNT4; SBAR;
      STAGE(par ^ 1, h, kofn + h * 64);
      COMPUTE(par, h);
    }
  }
  {
    const int par = (NT - 1) & 1;
    VMCNT4; SBAR; COMPUTE(par, 0);
    VMCNT0; SBAR; COMPUTE(par, 1);
  }

  // epilogue: +b1, relu, bf16 scatter to Hb rows = pair ids
  int hrow[8][4]; bool valid[8][4];
#pragma unroll
  for (int mf = 0; mf < 8; mf++)
#pragma unroll
    for (int rr = 0; rr < 4; rr++) {
      const int mi = m0 + wr * 128 + mf * 16 + lgrp * 4 + rr;
      valid[mf][rr] = (mi < cnt);
      hrow[mf][rr] = list[valid[mf][rr] ? mi : (cnt - 1)];
    }
#pragma unroll
  for (int nf = 0; nf < 4; nf++) {
    const int col = n0 + wc * 64 + nf * 16 + lrow;
    const float bias = b1[e * HDIM + col];
#pragma unroll
    for (int mf = 0; mf < 8; mf++)
#pragma unroll
      for (int rr = 0; rr < 4; rr++)
        if (valid[mf][rr]) {
          float h = acc[mf][nf][rr] + bias;
          h = h > 0.f ? h : 0.f;
          Hb[(size_t)hrow[mf][rr] * HDIM + col] = f2bf(h);
        }
  }
}

// ---------------- GEMM2: out[token] += w_pair*(Hb[pair] @ w2b[e]^T + b2) ----
__global__ __launch_bounds__(512, 2) void gemm2_8p_kernel(
    const unsigned short* __restrict__ Hb, const unsigned short* __restrict__ wb,
    const float* __restrict__ b2, const float* __restrict__ pair_w,
    const int* __restrict__ counts, const int* __restrict__ lists,
    float* __restrict__ out)
{
  int bx, by, bz;
  xcd_remap(bx, by, bz);
  const int e = bz / KS2, ks = bz % KS2;
  int cnt = counts[e]; if (cnt > CAP) cnt = CAP;
  const int m0 = by * BMG;
  if (m0 >= cnt) return;
  const int n0 = bx * BNG;
  const int* list = lists + e * CAP;
  const unsigned short* W = wb + (size_t)e * HDIM * CDIM;
  const int kbegb = ks * (HDIM / KS2) * 2;  // byte offset of K chunk

  __shared__ __align__(16) unsigned short lds[8 * SLOT];  // 128 KB

  const int t = threadIdx.x, w = t >> 6, lane = t & 63;
  const int wr = w >> 2, wc = w & 3;
  const int lrow = lane & 15, lgrp = lane >> 4;

  const int sr0 = w * 16 + (lane >> 2), sr1 = 128 + w * 16 + (lane >> 2);
  int ai0 = m0 + sr0; if (ai0 > cnt - 1) ai0 = cnt - 1;
  int ai1 = m0 + sr1; if (ai1 > cnt - 1) ai1 = cnt - 1;
  const char* agA0 = (const char*)(Hb + (size_t)list[ai0] * HDIM) + kbegb + (lane & 3) * 16;
  const char* agA1 = (const char*)(Hb + (size_t)list[ai1] * HDIM) + kbegb + (lane & 3) * 16;
  const char* bgB0 = (const char*)(W + (size_t)(n0 + sr0) * HDIM) + kbegb + (lane & 3) * 16;
  const char* bgB1 = (const char*)(W + (size_t)(n0 + sr1) * HDIM) + kbegb + (lane & 3) * 16;

  f32x4 acc[8][4] = {};

  const int NT = (HDIM / KS2) / 64;  // 32 K-tiles per chunk
  STAGE(0, 0, 0);
  STAGE(0, 1, 64);
  for (int tt = 0; tt < NT - 1; ++tt) {
    const int par = tt & 1;
    const int kofn = (tt + 1) * 128;
#pragma unroll
    for (int h = 0; h < 2; ++h) {
      VMCNT4; SBAR;
      STAGE(par ^ 1, h, kofn + h * 64);
      COMPUTE(par, h);
    }
  }
  {
    const int par = (NT - 1) & 1;
    VMCNT4; SBAR; COMPUTE(par, 0);
    VMCNT0; SBAR; COMPUTE(par, 1);
  }

  // epilogue: +b2 (ks==0 only), scale by routing weight, atomic accumulate.
  float wgt[8][4]; int tok[8][4]; bool valid[8][4];
#pragma unroll
  for (int mf = 0; mf < 8; mf++)
#pragma unroll
    for (int rr = 0; rr < 4; rr++) {
      const int mi = m0 + wr * 128 + mf * 16 + lgrp * 4 + rr;
      valid[mf][rr] = (mi < cnt);
      const int p = list[valid[mf][rr] ? mi : (cnt - 1)];
      wgt[mf][rr] = pair_w[p];
      tok[mf][rr] = p >> 1;
    }
#pragma unroll
  for (int nf = 0; nf < 4; nf++) {
    const int col = n0 + wc * 64 + nf * 16 + lrow;
    const float bias = (ks == 0) ? b2[e * CDIM + col] : 0.f;
#pragma unroll
    for (int mf = 0; mf < 8; mf++)
#pragma unroll
      for (int rr = 0; rr < 4; rr++)
        if (valid[mf][rr])
          atomicAdd(out + (size_t)tok[mf][rr] * CDIM + col,
                    wgt[mf][rr] * (acc[mf][nf][rr] + bias));
  }
}

// ================= fallback kernels (fp32 inputs, reg-staged, 128²) =========
typedef __attribute__((ext_vector_type(8))) unsigned short u16x8b;

__device__ __forceinline__ int swz(int row, int b) {
  return row * 128 + (b ^ (((row >> 1) & 7) << 4));
}

#define MFMA_COMPUTE_F(Abase, Bbase)                                           \
  _Pragma("unroll")                                                            \
  for (int kk = 0; kk < 2; kk++) {                                             \
    bf16x8 af[4], bfr[4];                                                      \
    const int kb = (kk * 32 + lgrp * 8) * 2;                                   \
    _Pragma("unroll")                                                          \
    for (int i = 0; i < 4; i++)                                                \
      af[i] = *(const bf16x8*)((Abase) + swz(wm + i * 16 + lrow, kb));         \
    _Pragma("unroll")                                                          \
    for (int j = 0; j < 4; j++)                                                \
      bfr[j] = *(const bf16x8*)((Bbase) + swz(wn + j * 16 + lrow, kb));        \
    _Pragma("unroll")                                                          \
    for (int i = 0; i < 4; i++)                                                \
      _Pragma("unroll")                                                        \
      for (int j = 0; j < 4; j++)                                              \
        acc[i][j] = __builtin_amdgcn_mfma_f32_16x16x32_bf16(                   \
            af[i], bfr[j], acc[i][j], 0, 0, 0);                                \
  }

__global__ __launch_bounds__(256) void gemm1_f32_kernel(
    const float* __restrict__ x, const float* __restrict__ w1,
    const float* __restrict__ b1, const int* __restrict__ counts,
    const int* __restrict__ lists, unsigned short* __restrict__ Hb,
    int e_base, int h_by_pair)
{
  const int e = e_base + blockIdx.z;
  int cnt = counts[e]; if (cnt > CAP) cnt = CAP;
  const int m0 = blockIdx.y * 128;
  if (m0 >= cnt) return;
  const int n0 = blockIdx.x * 128;
  const int* list = lists + e * CAP;
  const float* W = w1 + (size_t)e * CDIM * HDIM;
  __shared__ __align__(16) unsigned short As[128 * 64];
  __shared__ __align__(16) unsigned short Bs[128 * 64];
  const int t = threadIdx.x;
  const int a_row = t >> 1, a_half = t & 1;
  int a_idx = m0 + a_row; if (a_idx > cnt - 1) a_idx = cnt - 1;
  const float* a_src = x + (size_t)(list[a_idx] >> 1) * CDIM + a_half * 32;
  const int b_np = t & 63, b_kg = t >> 6;
  const int wid = t >> 6, lane = t & 63;
  const int wm = (wid >> 1) * 64, wn = (wid & 1) * 64;
  const int lrow = lane & 15, lgrp = lane >> 4;
  f32x4 acc[4][4] = {};
  for (int kt = 0; kt < CDIM; kt += 64) {
    {
      const float* s = a_src + kt;
      u16x8 cv[4];
#pragma unroll
      for (int q = 0; q < 4; q++) {
        float4 v0 = *(const float4*)(s + q * 8);
        float4 v1 = *(const float4*)(s + q * 8 + 4);
        cv[q][0] = f2bf(v0.x); cv[q][1] = f2bf(v0.y);
        cv[q][2] = f2bf(v0.z); cv[q][3] = f2bf(v0.w);
        cv[q][4] = f2bf(v1.x); cv[q][5] = f2bf(v1.y);
        cv[q][6] = f2bf(v1.z); cv[q][7] = f2bf(v1.w);
      }
#pragma unroll
      for (int q = 0; q < 4; q++)
        *(u16x8*)((char*)As + swz(a_row, (a_half * 32 + q * 8) * 2)) = cv[q];
    }
    {
#pragma unroll
      for (int it = 0; it < 2; it++) {
        const int k0 = (b_kg + 4 * it) * 8;
        u16x8 c0, c1;
#pragma unroll
        for (int j = 0; j < 8; j++) {
          float2 v = *(const float2*)(W + (size_t)(kt + k0 + j) * HDIM + n0 + 2 * b_np);
          c0[j] = f2bf(v.x); c1[j] = f2bf(v.y);
        }
        *(u16x8*)((char*)Bs + swz(2 * b_np,     k0 * 2)) = c0;
        *(u16x8*)((char*)Bs + swz(2 * b_np + 1, k0 * 2)) = c1;
      }
    }
    __syncthreads();
    MFMA_COMPUTE_F((const char*)As, (const char*)Bs)
    __syncthreads();
  }
  int hrow[4][4]; bool valid[4][4];
#pragma unroll
  for (int i = 0; i < 4; i++)
#pragma unroll
    for (int r = 0; r < 4; r++) {
      const int mi = m0 + wm + i * 16 + lgrp * 4 + r;
      valid[i][r] = (mi < cnt);
      const int idx = valid[i][r] ? mi : (cnt - 1);
      hrow[i][r] = h_by_pair ? list[idx] : idx;
    }
#pragma unroll
  for (int j = 0; j < 4; j++) {
    const int col = n0 + wn + j * 16 + lrow;
    const float bias = b1[e * HDIM + col];
#pragma unroll
    for (int i = 0; i < 4; i++)
#pragma unroll
      for (int r = 0; r < 4; r++)
        if (valid[i][r]) {
          float h = acc[i][j][r] + bias;
          h = h > 0.f ? h : 0.f;
          Hb[(size_t)hrow[i][r] * HDIM + col] = f2bf(h);
        }
  }
}

__global__ __launch_bounds__(256) void gemm2_f32_kernel(
    const unsigned short* __restrict__ Hb, const float* __restrict__ w2,
    const float* __restrict__ b2, const float* __restrict__ pair_w,
    const int* __restrict__ counts, const int* __restrict__ lists,
    float* __restrict__ out, int e_base, int h_by_pair)
{
  const int e = e_base + blockIdx.z;
  int cnt = counts[e]; if (cnt > CAP) cnt = CAP;
  const int m0 = blockIdx.y * 128;
  if (m0 >= cnt) return;
  const int n0 = blockIdx.x * 128;
  const int* list = lists + e * CAP;
  const float* W = w2 + (size_t)e * HDIM * CDIM;
  __shared__ __align__(16) unsigned short As[128 * 64];
  __shared__ __align__(16) unsigned short Bs[128 * 64];
  const int t = threadIdx.x;
  const int a_row = t >> 1, a_half = t & 1;
  int a_idx = m0 + a_row; if (a_idx > cnt - 1) a_idx = cnt - 1;
  const unsigned short* a_src =
      Hb + (size_t)(h_by_pair ? list[a_idx] : a_idx) * HDIM + a_half * 32;
  const int b_np = t & 63, b_kg = t >> 6;
  const int wid = t >> 6, lane = t & 63;
  const int wm = (wid >> 1) * 64, wn = (wid & 1) * 64;
  const int lrow = lane & 15, lgrp = lane >> 4;
  f32x4 acc[4][4] = {};
  for (int kt = 0; kt < HDIM; kt += 64) {
    {
      const unsigned short* s = a_src + kt;
#pragma unroll
      for (int q = 0; q < 4; q++) {
        u16x8 v = *(const u16x8*)(s + q * 8);
        *(u16x8*)((char*)As + swz(a_row, (a_half * 32 + q * 8) * 2)) = v;
      }
    }
    {
#pragma unroll
      for (int it = 0; it < 2; it++) {
        const int k0 = (b_kg + 4 * it) * 8;
        u16x8 c0, c1;
#pragma unroll
        for (int j = 0; j < 8; j++) {
          float2 v = *(const float2*)(W + (size_t)(kt + k0 + j) * CDIM + n0 + 2 * b_np);
          c0[j] = f2bf(v.x); c1[j] = f2bf(v.y);
        }
        *(u16x8*)((char*)Bs + swz(2 * b_np,     k0 * 2)) = c0;
        *(u16x8*)((char*)Bs + swz(2 * b_np + 1, k0 * 2)) = c1;
      }
    }
    __syncthreads();
    MFMA_COMPUTE_F((const char*)As, (const char*)Bs)
    __syncthreads();
  }
  float wgt[4][4]; int tok[4][4]; bool valid[4][4];
#pragma unroll
  for (int i = 0; i < 4; i++)
#pragma unroll
    for (int r = 0; r < 4; r++) {
      const int mi = m0 + wm + i * 16 + lgrp * 4 + r;
      valid[i][r] = (mi < cnt);
      const int idx = valid[i][r] ? mi : (cnt - 1);
      const int p = list[idx];
      wgt[i][r] = pair_w[p];
      tok[i][r] = p >> 1;
    }
#pragma unroll
  for (int j = 0; j < 4; j++) {
    const int col = n0 + wn + j * 16 + lrow;
    const float bias = b2[e * CDIM + col];
#pragma unroll
    for (int i = 0; i < 4; i++)
#pragma unroll
      for (int r = 0; r < 4; r++)
        if (valid[i][r])
          atomicAdd(out + (size_t)tok[i][r] * CDIM + col,
                    wgt[i][r] * (acc[i][j][r] + bias));
  }
}

extern "C" void kernel_launch(void* const* d_in, const int* in_sizes, int n_in,
                              void* d_out, int out_size, void* d_ws, size_t ws_size,
                              hipStream_t stream)
{
  const float* x  = (const float*)d_in[0];
  const float* wr = (const float*)d_in[1];
  const float* w1 = (const float*)d_in[2];
  const float* b1 = (const float*)d_in[3];
  const float* w2 = (const float*)d_in[4];
  const float* b2 = (const float*)d_in[5];
  float* out = (float*)d_out;

  const int N = in_sizes[0] / CDIM;  // 8192 tokens

  char* ws = (char*)d_ws;
  int* counts = (int*)ws;
  int* lists  = (int*)(ws + 256);
  float* pw   = (float*)(ws + 256 + NEXP * CAP * 4);
  size_t off = 256 + (size_t)NEXP * CAP * 4 + (size_t)2 * N * 4;
  off = (off + 255) & ~(size_t)255;
  unsigned short* xb = (unsigned short*)(ws + off);
  const size_t xb_sz = (size_t)N * CDIM * 2;
  unsigned short* Hb = (unsigned short*)(ws + off + xb_sz);
  const size_t Hb_sz = (size_t)2 * N * HDIM * 2;
  unsigned short* wb = (unsigned short*)(ws + off + xb_sz + Hb_sz);
  const size_t wb_sz = (size_t)NEXP * CDIM * HDIM * 2;

  const size_t need_new = off + xb_sz + Hb_sz + wb_sz;     // ~285 MB
  const size_t need_old = off + Hb_sz;                     // ~134.5 MB

  hipMemsetAsync(d_ws, 0, 64, stream);
  hipMemsetAsync(d_out, 0, (size_t)out_size * 4, stream);

  router_kernel<<<N, 64, 0, stream>>>(x, wr, pw, counts, lists);

  if (ws_size >= need_new) {
    cvt_x_kernel<<<(N * CDIM / 8 + 255) / 256, 256, 0, stream>>>(
        x, xb, N * CDIM / 8);
    transpose_cvt_kernel<<<dim3(HDIM / 64, CDIM / 64, NEXP), 256, 0, stream>>>(
        w1, wb, CDIM, HDIM);
    gemm1_8p_kernel<<<dim3(HDIM / BNG, CAP / BMG, NEXP), 512, 0, stream>>>(
        xb, wb, b1, counts, lists, Hb);
    transpose_cvt_kernel<<<dim3(CDIM / 64, HDIM / 64, NEXP), 256, 0, stream>>>(
        w2, wb, HDIM, CDIM);
    gemm2_8p_kernel<<<dim3(CDIM / BNG, CAP / BMG, NEXP * KS2), 512, 0, stream>>>(
        Hb, wb, b2, pw, counts, lists, out);
  } else if (ws_size >= need_old) {
    unsigned short* Hb0 = (unsigned short*)(ws + off);
    gemm1_f32_kernel<<<dim3(HDIM / 128, CAP / 128, NEXP), 256, 0, stream>>>(
        x, w1, b1, counts, lists, Hb0, 0, 1);
    gemm2_f32_kernel<<<dim3(CDIM / 128, CAP / 128, NEXP), 256, 0, stream>>>(
        Hb0, w2, b2, pw, counts, lists, out, 0, 1);
  }
}

// Round 6
// 921.481 us; speedup vs baseline: 1.1808x; 1.0174x over previous
//
#include <hip/hip_runtime.h>
#include <hip/hip_bf16.h>

// DynamicRouterMoE: N=8192 tokens, C=1024, Hdim=4096, E=16, top-2.
// R6: R5's 256x256 8-wave phase-split GEMMs + quad-XOR LDS swizzle
//     (q' = q ^ ((row>>1)&3)) applied BOTH sides: pre-swizzled global
//     source for global_load_lds (linear dest) + swizzled ds_read offset.
//     Kills the 8-way bank conflict (14.2M cycles) on the fragment reads.

typedef __attribute__((ext_vector_type(4))) float f32x4;
typedef __attribute__((ext_vector_type(8))) __bf16 bf16x8;
typedef __attribute__((ext_vector_type(8))) unsigned short u16x8;

#define NEXP 16
#define CAP  2048
#define CDIM 1024
#define HDIM 4096
#define KS2 2            // split-K factor for gemm2
#define BMG 256          // GEMM tile M
#define BNG 256          // GEMM tile N
#define SLOT 8192        // elems per LDS slot: 256 rows x 32 k

__device__ __forceinline__ unsigned short f2bf(float f) {
  return __builtin_bit_cast(unsigned short, (__bf16)f);
}

typedef __attribute__((address_space(3))) void  lds_void;
typedef __attribute__((address_space(1))) const void gbl_void;
__device__ __forceinline__ void gload16(const void* g, void* l) {
  __builtin_amdgcn_global_load_lds((gbl_void*)g, (lds_void*)l, 16, 0, 0);
}

// Bijective XCD swizzle (requires nwg % 8 == 0; true for all GEMM grids).
__device__ __forceinline__ void xcd_remap(int& bx, int& by, int& bz) {
  const int gx = gridDim.x, gy = gridDim.y;
  const int nwg = gx * gy * gridDim.z;
  int flat = blockIdx.x + gx * (blockIdx.y + gy * blockIdx.z);
  flat = (flat & 7) * (nwg >> 3) + (flat >> 3);
  bx = flat % gx;
  const int t = flat / gx;
  by = t % gy;
  bz = t / gy;
}

// ---------------- router: logits(fp64) -> top2 -> softmax -> lists ----------
__global__ __launch_bounds__(64) void router_kernel(
    const float* __restrict__ x, const float* __restrict__ wr,
    float* __restrict__ pair_w, int* __restrict__ counts,
    int* __restrict__ lists)
{
  const int n = blockIdx.x;
  const int l = threadIdx.x;
  const float* xrow = x + (size_t)n * CDIM;
  double acc[NEXP];
#pragma unroll
  for (int e = 0; e < NEXP; e++) acc[e] = 0.0;
  for (int it = 0; it < CDIM / 64; it++) {
    const int c = l + it * 64;
    const double xv = (double)xrow[c];
    const float* w = wr + c * NEXP;
#pragma unroll
    for (int e = 0; e < NEXP; e++) acc[e] += xv * (double)w[e];
  }
#pragma unroll
  for (int e = 0; e < NEXP; e++) {
    double v = acc[e];
    for (int off = 32; off > 0; off >>= 1) v += __shfl_xor(v, off, 64);
    acc[e] = v;
  }
  if (l == 0) {
    int e0 = 0; double b0 = acc[0];
    for (int e = 1; e < NEXP; e++) if (acc[e] > b0) { b0 = acc[e]; e0 = e; }
    int e1 = -1; double b1v = -1e300;
    for (int e = 0; e < NEXP; e++) {
      if (e == e0) continue;
      if (acc[e] > b1v) { b1v = acc[e]; e1 = e; }
    }
    const double d = exp(b1v - b0);
    pair_w[2 * n]     = (float)(1.0 / (1.0 + d));
    pair_w[2 * n + 1] = (float)(d / (1.0 + d));
    int p0 = atomicAdd(&counts[e0], 1);
    if (p0 < CAP) lists[e0 * CAP + p0] = 2 * n;
    int p1 = atomicAdd(&counts[e1], 1);
    if (p1 < CAP) lists[e1 * CAP + p1] = 2 * n + 1;
  }
}

// ---------------- convert x -> bf16 ----------------------------------------
__global__ __launch_bounds__(256) void cvt_x_kernel(
    const float* __restrict__ x, unsigned short* __restrict__ xb, int n8)
{
  const int i = blockIdx.x * 256 + threadIdx.x;
  if (i >= n8) return;
  float4 a = ((const float4*)x)[2 * i];
  float4 b = ((const float4*)x)[2 * i + 1];
  u16x8 v;
  v[0] = f2bf(a.x); v[1] = f2bf(a.y); v[2] = f2bf(a.z); v[3] = f2bf(a.w);
  v[4] = f2bf(b.x); v[5] = f2bf(b.y); v[6] = f2bf(b.z); v[7] = f2bf(b.w);
  ((u16x8*)xb)[i] = v;
}

// ------------- transpose+convert: src fp32 [K][Nn] -> dst bf16 [Nn][K] ------
__global__ __launch_bounds__(256) void transpose_cvt_kernel(
    const float* __restrict__ src, unsigned short* __restrict__ dst,
    int K, int Nn)
{
  __shared__ __align__(16) unsigned short tile[64][72];  // +8 pad
  const size_t eoff = (size_t)blockIdx.z * K * Nn;
  const float* S = src + eoff;
  unsigned short* D = dst + eoff;
  const int n0 = blockIdx.x * 64, k0 = blockIdx.y * 64;
  const int t = threadIdx.x;
  {
    const int nl = (t & 15) * 4, kr = t >> 4;
#pragma unroll
    for (int p = 0; p < 4; p++) {
      const int k = kr + p * 16;
      float4 v = *(const float4*)(S + (size_t)(k0 + k) * Nn + n0 + nl);
      tile[nl + 0][k] = f2bf(v.x);
      tile[nl + 1][k] = f2bf(v.y);
      tile[nl + 2][k] = f2bf(v.z);
      tile[nl + 3][k] = f2bf(v.w);
    }
  }
  __syncthreads();
  {
    const int kq = (t & 7) * 8, nr = t >> 3;
#pragma unroll
    for (int p = 0; p < 2; p++) {
      const int n = nr + p * 32;
      u16x8 v = *(const u16x8*)&tile[n][kq];
      *(u16x8*)(D + (size_t)(n0 + n) * K + k0 + kq) = v;
    }
  }
}

// ========= 8-wave 256x256 phase-split GEMM bodies ==========================
// LDS: A slots [par][kh][256 rows][32 k] then B slots; slot = 16KB, 64B rows.
// Quad-XOR swizzle: LDS(row, q') holds global quad q = q' ^ ((row>>1)&3).
// Write side realizes it by pre-XORing the per-lane GLOBAL source quad
// (dest stays linear lane*16, as global_load_lds requires). Read side
// XORs the 16B-quad select. Per ds_read_b128: rows 0..7 of each 16-row
// group now cover all 8 bank-quads -> 2-way (free) instead of 8-way.

#define STAGE(parx, hx, koffb)                                                 \
  do {                                                                         \
    unsigned short* Ad = &lds[((parx) * 2 + (hx)) * SLOT + w * 512];           \
    unsigned short* Bd = &lds[4 * SLOT + ((parx) * 2 + (hx)) * SLOT + w * 512];\
    gload16(agA0 + (koffb), Ad);                                               \
    gload16(agA1 + (koffb), Ad + 4096);                                        \
    gload16(bgB0 + (koffb), Bd);                                               \
    gload16(bgB1 + (koffb), Bd + 4096);                                        \
  } while (0)

#define COMPUTE(parx, hx)                                                      \
  do {                                                                         \
    const unsigned short* As_ = &lds[((parx) * 2 + (hx)) * SLOT];              \
    const unsigned short* Bs_ = &lds[4 * SLOT + ((parx) * 2 + (hx)) * SLOT];   \
    bf16x8 af[8], bfv[4];                                                      \
    _Pragma("unroll")                                                          \
    for (int mf = 0; mf < 8; mf++)                                             \
      af[mf] = *(const bf16x8*)(As_ + (wr * 128 + mf * 16 + lrow) * 32 + qsw); \
    _Pragma("unroll")                                                          \
    for (int nf = 0; nf < 4; nf++)                                             \
      bfv[nf] = *(const bf16x8*)(Bs_ + (wc * 64 + nf * 16 + lrow) * 32 + qsw); \
    __builtin_amdgcn_s_setprio(1);                                             \
    _Pragma("unroll")                                                          \
    for (int mf = 0; mf < 8; mf++)                                             \
      _Pragma("unroll")                                                        \
      for (int nf = 0; nf < 4; nf++)                                           \
        acc[mf][nf] = __builtin_amdgcn_mfma_f32_16x16x32_bf16(                 \
            af[mf], bfv[nf], acc[mf][nf], 0, 0, 0);                            \
    __builtin_amdgcn_s_setprio(0);                                             \
  } while (0)

#define VMCNT4 asm volatile("s_waitcnt vmcnt(4)" ::: "memory")
#define VMCNT0 asm volatile("s_waitcnt vmcnt(0)" ::: "memory")
#define SBAR   asm volatile("s_barrier" ::: "memory")

// ---------------- GEMM1: H[pair] = relu(xb[token] @ w1b[e]^T + b1[e]) -------
__global__ __launch_bounds__(512, 2) void gemm1_8p_kernel(
    const unsigned short* __restrict__ xb, const unsigned short* __restrict__ wb,
    const float* __restrict__ b1, const int* __restrict__ counts,
    const int* __restrict__ lists, unsigned short* __restrict__ Hb)
{
  int bx, by, bz;
  xcd_remap(bx, by, bz);
  const int e = bz;
  int cnt = counts[e]; if (cnt > CAP) cnt = CAP;
  const int m0 = by * BMG;
  if (m0 >= cnt) return;
  const int n0 = bx * BNG;
  const int* list = lists + e * CAP;
  const unsigned short* W = wb + (size_t)e * CDIM * HDIM;

  __shared__ __align__(16) unsigned short lds[8 * SLOT];  // 128 KB

  const int t = threadIdx.x, w = t >> 6, lane = t & 63;
  const int wr = w >> 2, wc = w & 3;          // 2M x 4N waves, each 128x64
  const int lrow = lane & 15, lgrp = lane >> 4;
  // read-side swizzled 16B-quad select (elements): (row>>1)&3 == (lrow>>1)&3
  const int qsw = (lgrp ^ ((lrow >> 1) & 3)) * 8;

  // staging: thread covers rows r(j) = j*128 + w*16 + lane/4; global quad
  // pre-XORed so linear LDS dest realizes the swizzled layout.
  const int sr0 = w * 16 + (lane >> 2), sr1 = 128 + w * 16 + (lane >> 2);
  const int sq = ((lane & 3) ^ ((lane >> 3) & 3)) * 16;  // byte offset
  int ai0 = m0 + sr0; if (ai0 > cnt - 1) ai0 = cnt - 1;
  int ai1 = m0 + sr1; if (ai1 > cnt - 1) ai1 = cnt - 1;
  const char* agA0 = (const char*)(xb + (size_t)(list[ai0] >> 1) * CDIM) + sq;
  const char* agA1 = (const char*)(xb + (size_t)(list[ai1] >> 1) * CDIM) + sq;
  const char* bgB0 = (const char*)(W + (size_t)(n0 + sr0) * CDIM) + sq;
  const char* bgB1 = (const char*)(W + (size_t)(n0 + sr1) * CDIM) + sq;

  f32x4 acc[8][4] = {};

  const int NT = CDIM / 64;  // 16 K-tiles
  STAGE(0, 0, 0);
  STAGE(0, 1, 64);
  for (int tt = 0; tt < NT - 1; ++tt) {
    const int par = tt & 1;
    const int kofn = (tt + 1) * 128;
#pragma unroll
    for (int h = 0; h < 2; ++h) {
      VMCNT4; SBAR;
      STAGE(par ^ 1, h, kofn + h * 64);
      COMPUTE(par, h);
    }
  }
  {
    const int par = (NT - 1) & 1;
    VMCNT4; SBAR; COMPUTE(par, 0);
    VMCNT0; SBAR; COMPUTE(par, 1);
  }

  // epilogue: +b1, relu, bf16 scatter to Hb rows = pair ids
  int hrow[8][4]; bool valid[8][4];
#pragma unroll
  for (int mf = 0; mf < 8; mf++)
#pragma unroll
    for (int rr = 0; rr < 4; rr++) {
      const int mi = m0 + wr * 128 + mf * 16 + lgrp * 4 + rr;
      valid[mf][rr] = (mi < cnt);
      hrow[mf][rr] = list[valid[mf][rr] ? mi : (cnt - 1)];
    }
#pragma unroll
  for (int nf = 0; nf < 4; nf++) {
    const int col = n0 + wc * 64 + nf * 16 + lrow;
    const float bias = b1[e * HDIM + col];
#pragma unroll
    for (int mf = 0; mf < 8; mf++)
#pragma unroll
      for (int rr = 0; rr < 4; rr++)
        if (valid[mf][rr]) {
          float h = acc[mf][nf][rr] + bias;
          h = h > 0.f ? h : 0.f;
          Hb[(size_t)hrow[mf][rr] * HDIM + col] = f2bf(h);
        }
  }
}

// ---------------- GEMM2: out[token] += w_pair*(Hb[pair] @ w2b[e]^T + b2) ----
__global__ __launch_bounds__(512, 2) void gemm2_8p_kernel(
    const unsigned short* __restrict__ Hb, const unsigned short* __restrict__ wb,
    const float* __restrict__ b2, const float* __restrict__ pair_w,
    const int* __restrict__ counts, const int* __restrict__ lists,
    float* __restrict__ out)
{
  int bx, by, bz;
  xcd_remap(bx, by, bz);
  const int e = bz / KS2, ks = bz % KS2;
  int cnt = counts[e]; if (cnt > CAP) cnt = CAP;
  const int m0 = by * BMG;
  if (m0 >= cnt) return;
  const int n0 = bx * BNG;
  const int* list = lists + e * CAP;
  const unsigned short* W = wb + (size_t)e * HDIM * CDIM;
  const int kbegb = ks * (HDIM / KS2) * 2;  // byte offset of K chunk

  __shared__ __align__(16) unsigned short lds[8 * SLOT];  // 128 KB

  const int t = threadIdx.x, w = t >> 6, lane = t & 63;
  const int wr = w >> 2, wc = w & 3;
  const int lrow = lane & 15, lgrp = lane >> 4;
  const int qsw = (lgrp ^ ((lrow >> 1) & 3)) * 8;

  const int sr0 = w * 16 + (lane >> 2), sr1 = 128 + w * 16 + (lane >> 2);
  const int sq = ((lane & 3) ^ ((lane >> 3) & 3)) * 16;
  int ai0 = m0 + sr0; if (ai0 > cnt - 1) ai0 = cnt - 1;
  int ai1 = m0 + sr1; if (ai1 > cnt - 1) ai1 = cnt - 1;
  const char* agA0 = (const char*)(Hb + (size_t)list[ai0] * HDIM) + kbegb + sq;
  const char* agA1 = (const char*)(Hb + (size_t)list[ai1] * HDIM) + kbegb + sq;
  const char* bgB0 = (const char*)(W + (size_t)(n0 + sr0) * HDIM) + kbegb + sq;
  const char* bgB1 = (const char*)(W + (size_t)(n0 + sr1) * HDIM) + kbegb + sq;

  f32x4 acc[8][4] = {};

  const int NT = (HDIM / KS2) / 64;  // 32 K-tiles per chunk
  STAGE(0, 0, 0);
  STAGE(0, 1, 64);
  for (int tt = 0; tt < NT - 1; ++tt) {
    const int par = tt & 1;
    const int kofn = (tt + 1) * 128;
#pragma unroll
    for (int h = 0; h < 2; ++h) {
      VMCNT4; SBAR;
      STAGE(par ^ 1, h, kofn + h * 64);
      COMPUTE(par, h);
    }
  }
  {
    const int par = (NT - 1) & 1;
    VMCNT4; SBAR; COMPUTE(par, 0);
    VMCNT0; SBAR; COMPUTE(par, 1);
  }

  // epilogue: +b2 (ks==0 only), scale by routing weight, atomic accumulate.
  float wgt[8][4]; int tok[8][4]; bool valid[8][4];
#pragma unroll
  for (int mf = 0; mf < 8; mf++)
#pragma unroll
    for (int rr = 0; rr < 4; rr++) {
      const int mi = m0 + wr * 128 + mf * 16 + lgrp * 4 + rr;
      valid[mf][rr] = (mi < cnt);
      const int p = list[valid[mf][rr] ? mi : (cnt - 1)];
      wgt[mf][rr] = pair_w[p];
      tok[mf][rr] = p >> 1;
    }
#pragma unroll
  for (int nf = 0; nf < 4; nf++) {
    const int col = n0 + wc * 64 + nf * 16 + lrow;
    const float bias = (ks == 0) ? b2[e * CDIM + col] : 0.f;
#pragma unroll
    for (int mf = 0; mf < 8; mf++)
#pragma unroll
      for (int rr = 0; rr < 4; rr++)
        if (valid[mf][rr])
          atomicAdd(out + (size_t)tok[mf][rr] * CDIM + col,
                    wgt[mf][rr] * (acc[mf][nf][rr] + bias));
  }
}

// ================= fallback kernels (fp32 inputs, reg-staged, 128²) =========
__device__ __forceinline__ int swz(int row, int b) {
  return row * 128 + (b ^ (((row >> 1) & 7) << 4));
}

#define MFMA_COMPUTE_F(Abase, Bbase)                                           \
  _Pragma("unroll")                                                            \
  for (int kk = 0; kk < 2; kk++) {                                             \
    bf16x8 af[4], bfr[4];                                                      \
    const int kb = (kk * 32 + lgrp * 8) * 2;                                   \
    _Pragma("unroll")                                                          \
    for (int i = 0; i < 4; i++)                                                \
      af[i] = *(const bf16x8*)((Abase) + swz(wm + i * 16 + lrow, kb));         \
    _Pragma("unroll")                                                          \
    for (int j = 0; j < 4; j++)                                                \
      bfr[j] = *(const bf16x8*)((Bbase) + swz(wn + j * 16 + lrow, kb));        \
    _Pragma("unroll")                                                          \
    for (int i = 0; i < 4; i++)                                                \
      _Pragma("unroll")                                                        \
      for (int j = 0; j < 4; j++)                                              \
        acc[i][j] = __builtin_amdgcn_mfma_f32_16x16x32_bf16(                   \
            af[i], bfr[j], acc[i][j], 0, 0, 0);                                \
  }

__global__ __launch_bounds__(256) void gemm1_f32_kernel(
    const float* __restrict__ x, const float* __restrict__ w1,
    const float* __restrict__ b1, const int* __restrict__ counts,
    const int* __restrict__ lists, unsigned short* __restrict__ Hb,
    int e_base, int h_by_pair)
{
  const int e = e_base + blockIdx.z;
  int cnt = counts[e]; if (cnt > CAP) cnt = CAP;
  const int m0 = blockIdx.y * 128;
  if (m0 >= cnt) return;
  const int n0 = blockIdx.x * 128;
  const int* list = lists + e * CAP;
  const float* W = w1 + (size_t)e * CDIM * HDIM;
  __shared__ __align__(16) unsigned short As[128 * 64];
  __shared__ __align__(16) unsigned short Bs[128 * 64];
  const int t = threadIdx.x;
  const int a_row = t >> 1, a_half = t & 1;
  int a_idx = m0 + a_row; if (a_idx > cnt - 1) a_idx = cnt - 1;
  const float* a_src = x + (size_t)(list[a_idx] >> 1) * CDIM + a_half * 32;
  const int b_np = t & 63, b_kg = t >> 6;
  const int wid = t >> 6, lane = t & 63;
  const int wm = (wid >> 1) * 64, wn = (wid & 1) * 64;
  const int lrow = lane & 15, lgrp = lane >> 4;
  f32x4 acc[4][4] = {};
  for (int kt = 0; kt < CDIM; kt += 64) {
    {
      const float* s = a_src + kt;
      u16x8 cv[4];
#pragma unroll
      for (int q = 0; q < 4; q++) {
        float4 v0 = *(const float4*)(s + q * 8);
        float4 v1 = *(const float4*)(s + q * 8 + 4);
        cv[q][0] = f2bf(v0.x); cv[q][1] = f2bf(v0.y);
        cv[q][2] = f2bf(v0.z); cv[q][3] = f2bf(v0.w);
        cv[q][4] = f2bf(v1.x); cv[q][5] = f2bf(v1.y);
        cv[q][6] = f2bf(v1.z); cv[q][7] = f2bf(v1.w);
      }
#pragma unroll
      for (int q = 0; q < 4; q++)
        *(u16x8*)((char*)As + swz(a_row, (a_half * 32 + q * 8) * 2)) = cv[q];
    }
    {
#pragma unroll
      for (int it = 0; it < 2; it++) {
        const int k0 = (b_kg + 4 * it) * 8;
        u16x8 c0, c1;
#pragma unroll
        for (int j = 0; j < 8; j++) {
          float2 v = *(const float2*)(W + (size_t)(kt + k0 + j) * HDIM + n0 + 2 * b_np);
          c0[j] = f2bf(v.x); c1[j] = f2bf(v.y);
        }
        *(u16x8*)((char*)Bs + swz(2 * b_np,     k0 * 2)) = c0;
        *(u16x8*)((char*)Bs + swz(2 * b_np + 1, k0 * 2)) = c1;
      }
    }
    __syncthreads();
    MFMA_COMPUTE_F((const char*)As, (const char*)Bs)
    __syncthreads();
  }
  int hrow[4][4]; bool valid[4][4];
#pragma unroll
  for (int i = 0; i < 4; i++)
#pragma unroll
    for (int r = 0; r < 4; r++) {
      const int mi = m0 + wm + i * 16 + lgrp * 4 + r;
      valid[i][r] = (mi < cnt);
      const int idx = valid[i][r] ? mi : (cnt - 1);
      hrow[i][r] = h_by_pair ? list[idx] : idx;
    }
#pragma unroll
  for (int j = 0; j < 4; j++) {
    const int col = n0 + wn + j * 16 + lrow;
    const float bias = b1[e * HDIM + col];
#pragma unroll
    for (int i = 0; i < 4; i++)
#pragma unroll
      for (int r = 0; r < 4; r++)
        if (valid[i][r]) {
          float h = acc[i][j][r] + bias;
          h = h > 0.f ? h : 0.f;
          Hb[(size_t)hrow[i][r] * HDIM + col] = f2bf(h);
        }
  }
}

__global__ __launch_bounds__(256) void gemm2_f32_kernel(
    const unsigned short* __restrict__ Hb, const float* __restrict__ w2,
    const float* __restrict__ b2, const float* __restrict__ pair_w,
    const int* __restrict__ counts, const int* __restrict__ lists,
    float* __restrict__ out, int e_base, int h_by_pair)
{
  const int e = e_base + blockIdx.z;
  int cnt = counts[e]; if (cnt > CAP) cnt = CAP;
  const int m0 = blockIdx.y * 128;
  if (m0 >= cnt) return;
  const int n0 = blockIdx.x * 128;
  const int* list = lists + e * CAP;
  const float* W = w2 + (size_t)e * HDIM * CDIM;
  __shared__ __align__(16) unsigned short As[128 * 64];
  __shared__ __align__(16) unsigned short Bs[128 * 64];
  const int t = threadIdx.x;
  const int a_row = t >> 1, a_half = t & 1;
  int a_idx = m0 + a_row; if (a_idx > cnt - 1) a_idx = cnt - 1;
  const unsigned short* a_src =
      Hb + (size_t)(h_by_pair ? list[a_idx] : a_idx) * HDIM + a_half * 32;
  const int b_np = t & 63, b_kg = t >> 6;
  const int wid = t >> 6, lane = t & 63;
  const int wm = (wid >> 1) * 64, wn = (wid & 1) * 64;
  const int lrow = lane & 15, lgrp = lane >> 4;
  f32x4 acc[4][4] = {};
  for (int kt = 0; kt < HDIM; kt += 64) {
    {
      const unsigned short* s = a_src + kt;
#pragma unroll
      for (int q = 0; q < 4; q++) {
        u16x8 v = *(const u16x8*)(s + q * 8);
        *(u16x8*)((char*)As + swz(a_row, (a_half * 32 + q * 8) * 2)) = v;
      }
    }
    {
#pragma unroll
      for (int it = 0; it < 2; it++) {
        const int k0 = (b_kg + 4 * it) * 8;
        u16x8 c0, c1;
#pragma unroll
        for (int j = 0; j < 8; j++) {
          float2 v = *(const float2*)(W + (size_t)(kt + k0 + j) * CDIM + n0 + 2 * b_np);
          c0[j] = f2bf(v.x); c1[j] = f2bf(v.y);
        }
        *(u16x8*)((char*)Bs + swz(2 * b_np,     k0 * 2)) = c0;
        *(u16x8*)((char*)Bs + swz(2 * b_np + 1, k0 * 2)) = c1;
      }
    }
    __syncthreads();
    MFMA_COMPUTE_F((const char*)As, (const char*)Bs)
    __syncthreads();
  }
  float wgt[4][4]; int tok[4][4]; bool valid[4][4];
#pragma unroll
  for (int i = 0; i < 4; i++)
#pragma unroll
    for (int r = 0; r < 4; r++) {
      const int mi = m0 + wm + i * 16 + lgrp * 4 + r;
      valid[i][r] = (mi < cnt);
      const int idx = valid[i][r] ? mi : (cnt - 1);
      const int p = list[idx];
      wgt[i][r] = pair_w[p];
      tok[i][r] = p >> 1;
    }
#pragma unroll
  for (int j = 0; j < 4; j++) {
    const int col = n0 + wn + j * 16 + lrow;
    const float bias = b2[e * CDIM + col];
#pragma unroll
    for (int i = 0; i < 4; i++)
#pragma unroll
      for (int r = 0; r < 4; r++)
        if (valid[i][r])
          atomicAdd(out + (size_t)tok[i][r] * CDIM + col,
                    wgt[i][r] * (acc[i][j][r] + bias));
  }
}

extern "C" void kernel_launch(void* const* d_in, const int* in_sizes, int n_in,
                              void* d_out, int out_size, void* d_ws, size_t ws_size,
                              hipStream_t stream)
{
  const float* x  = (const float*)d_in[0];
  const float* wr = (const float*)d_in[1];
  const float* w1 = (const float*)d_in[2];
  const float* b1 = (const float*)d_in[3];
  const float* w2 = (const float*)d_in[4];
  const float* b2 = (const float*)d_in[5];
  float* out = (float*)d_out;

  const int N = in_sizes[0] / CDIM;  // 8192 tokens

  char* ws = (char*)d_ws;
  int* counts = (int*)ws;
  int* lists  = (int*)(ws + 256);
  float* pw   = (float*)(ws + 256 + NEXP * CAP * 4);
  size_t off = 256 + (size_t)NEXP * CAP * 4 + (size_t)2 * N * 4;
  off = (off + 255) & ~(size_t)255;
  unsigned short* xb = (unsigned short*)(ws + off);
  const size_t xb_sz = (size_t)N * CDIM * 2;
  unsigned short* Hb = (unsigned short*)(ws + off + xb_sz);
  const size_t Hb_sz = (size_t)2 * N * HDIM * 2;
  unsigned short* wb = (unsigned short*)(ws + off + xb_sz + Hb_sz);
  const size_t wb_sz = (size_t)NEXP * CDIM * HDIM * 2;

  const size_t need_new = off + xb_sz + Hb_sz + wb_sz;     // ~285 MB
  const size_t need_old = off + Hb_sz;                     // ~134.5 MB

  hipMemsetAsync(d_ws, 0, 64, stream);
  hipMemsetAsync(d_out, 0, (size_t)out_size * 4, stream);

  router_kernel<<<N, 64, 0, stream>>>(x, wr, pw, counts, lists);

  if (ws_size >= need_new) {
    cvt_x_kernel<<<(N * CDIM / 8 + 255) / 256, 256, 0, stream>>>(
        x, xb, N * CDIM / 8);
    transpose_cvt_kernel<<<dim3(HDIM / 64, CDIM / 64, NEXP), 256, 0, stream>>>(
        w1, wb, CDIM, HDIM);
    gemm1_8p_kernel<<<dim3(HDIM / BNG, CAP / BMG, NEXP), 512, 0, stream>>>(
        xb, wb, b1, counts, lists, Hb);
    transpose_cvt_kernel<<<dim3(CDIM / 64, HDIM / 64, NEXP), 256, 0, stream>>>(
        w2, wb, HDIM, CDIM);
    gemm2_8p_kernel<<<dim3(CDIM / BNG, CAP / BMG, NEXP * KS2), 512, 0, stream>>>(
        Hb, wb, b2, pw, counts, lists, out);
  } else if (ws_size >= need_old) {
    unsigned short* Hb0 = (unsigned short*)(ws + off);
    gemm1_f32_kernel<<<dim3(HDIM / 128, CAP / 128, NEXP), 256, 0, stream>>>(
        x, w1, b1, counts, lists, Hb0, 0, 1);
    gemm2_f32_kernel<<<dim3(CDIM / 128, CAP / 128, NEXP), 256, 0, stream>>>(
        Hb0, w2, b2, pw, counts, lists, out, 0, 1);
  }
}